// Round 2
// baseline (2006.178 us; speedup 1.0000x reference)
//
#include <hip/hip_runtime.h>
#include <math.h>

#define NTHREADS 256
constexpr int TB = 4096;   // batch
constexpr int TT = 96;     // time
constexpr int TN = 32;     // channels
constexpr int NBINS = 49;  // rfft bins for T=96
constexpr int XLD = 33;    // padded LDS leading dim

struct Params {
    const float* x; const float* noise;
    const float* w_start; const float* b_start;
    const float* wg; const float* bg; const float* wn; const float* bn;
    const float* ew[16];   // e0_w1,e0_b1,e0_w2,e0_b2, e1_w1, ...
    float* out; float* part;
};

__device__ __forceinline__ float gelu_f(float v) {
    // jax.nn.gelu approximate=True (tanh form); tanh via fast exp
    float u = 0.7978845608028654f * (v + 0.044715f * v * v * v);
    float e = __expf(2.0f * u);
    float th = 1.0f - 2.0f / (e + 1.0f);
    return 0.5f * v * (1.0f + th);
}

template<int P>
__device__ __forceinline__ void run_expert(const float* __restrict__ xs,
        float* __restrict__ outsh, const float* __restrict__ wsh,
        int w1o, int w2o, int b1o, int b2o, float g, int tid) {
    constexpr int NTASK = (TT / P) * TN;
    for (int task = tid; task < NTASK; task += NTHREADS) {
        const int n  = task & 31;
        const int tb = task >> 5;
        float v[P];
        #pragma unroll
        for (int l = 0; l < P; ++l) v[l] = xs[(tb * P + l) * XLD + n];
        float h[32];
        #pragma unroll
        for (int j = 0; j < 32; ++j) {
            float a = wsh[b1o + j];
            #pragma unroll
            for (int l = 0; l < P; ++l) a = fmaf(v[l], wsh[w1o + l * 32 + j], a);
            h[j] = gelu_f(a);
        }
        #pragma unroll
        for (int l = 0; l < P; ++l) {
            float y = wsh[b2o + l];
            #pragma unroll
            for (int j = 0; j < 32; ++j) y = fmaf(h[j], wsh[w2o + j * P + l], y);
            outsh[(tb * P + l) * XLD + n] += g * y;
        }
    }
}

__global__ __launch_bounds__(NTHREADS, 4) void ams_main(Params p) {
    __shared__ float xs[TT * XLD];       // x2 tile (row t stride 33)
    __shared__ float ct[96], st[96];     // twiddles cos/sin(2*pi*m/96)
    __shared__ float xlin[96];
    __shared__ float frfi[3200];         // fr[n*50+k], fi at +1600; later aliased as outsh
    __shared__ float selr[256], seli[256];
    __shared__ int   selk[256];
    __shared__ int   selcnt[32];
    __shared__ float wsh[2080];          // all expert weights
    __shared__ float wst[32];
    __shared__ float gtmp[8];            // clean[4], rn[4]
    __shared__ float gsh[4];
    __shared__ float b0sh;

    const int tid = threadIdx.x;
    const int b = blockIdx.x;

    // ---------------- Phase A: stage x, weights, twiddles ----------------
    const float* xb = p.x + (size_t)b * (TT * TN);
    for (int idx = tid; idx < TT * TN; idx += NTHREADS)
        xs[(idx >> 5) * XLD + (idx & 31)] = xb[idx];
    if (tid < 96) {
        float ang = (float)tid * 0.06544984694978735f;  // 2*pi/96
        ct[tid] = cosf(ang);
        st[tid] = sinf(ang);
    }
    {
        constexpr int PP[4]  = {8, 6, 4, 12};
        constexpr int W1O[4] = {0, 256, 448, 576};
        constexpr int W2O[4] = {960, 1216, 1408, 1536};
        constexpr int B1O[4] = {1920, 1952, 1984, 2016};
        constexpr int B2O[4] = {2048, 2056, 2062, 2066};
        #pragma unroll
        for (int i = 0; i < 4; ++i) {
            const float* w1 = p.ew[4 * i + 0];
            const float* b1 = p.ew[4 * i + 1];
            const float* w2 = p.ew[4 * i + 2];
            const float* b2 = p.ew[4 * i + 3];
            for (int j = tid; j < PP[i] * 32; j += NTHREADS) wsh[W1O[i] + j] = w1[j];
            for (int j = tid; j < 32;         j += NTHREADS) wsh[B1O[i] + j] = b1[j];
            for (int j = tid; j < PP[i] * 32; j += NTHREADS) wsh[W2O[i] + j] = w2[j];
            for (int j = tid; j < PP[i];      j += NTHREADS) wsh[B2O[i] + j] = b2[j];
        }
    }
    if (tid < 32) wst[tid] = p.w_start[tid];
    if (tid == 0) b0sh = p.b_start[0];
    __syncthreads();

    // ---------------- Phase C: real DFT via register rotation ----------------
    // thread -> (n = tid>>3, kslot = tid&7), bins k = kslot + 8*j, j=0..6
    {
        const int n = tid >> 3;
        const int kslot = tid & 7;
        float c[7], s[7], ar[7], ai[7], ck[7], sk[7];
        #pragma unroll
        for (int j = 0; j < 7; ++j) {
            int k = kslot + 8 * j;
            c[j] = 1.0f; s[j] = 0.0f; ar[j] = 0.0f; ai[j] = 0.0f;
            if (k < NBINS) { ck[j] = ct[k]; sk[j] = st[k]; }
            else           { ck[j] = 1.0f;  sk[j] = 0.0f; }
        }
        for (int t = 0; t < TT; ++t) {
            float xv = xs[t * XLD + n];
            #pragma unroll
            for (int j = 0; j < 7; ++j) {
                ar[j] = fmaf(xv, c[j], ar[j]);      // sum x*cos
                ai[j] = fmaf(xv, s[j], ai[j]);      // sum x*sin
                float t0 = s[j] * sk[j];
                float t1 = c[j] * sk[j];
                float cn = fmaf(c[j], ck[j], -t0);  // rotate by 2*pi*k/96
                float sn = fmaf(s[j], ck[j],  t1);
                c[j] = cn; s[j] = sn;
            }
        }
        #pragma unroll
        for (int j = 0; j < 7; ++j) {
            int k = kslot + 8 * j;
            if (k < NBINS) {
                frfi[n * 50 + k]        = ar[j];
                frfi[1600 + n * 50 + k] = ai[j];
            }
        }
    }
    __syncthreads();

    // ---------------- Phase D: per-series top-3 amplitude selection ----------------
    if (tid < 32) {
        const int n = tid;
        const float* fr = &frfi[n * 50];
        const float* fi = &frfi[1600 + n * 50];
        float v1 = -1.0f, v2 = -1.0f, v3 = -1.0f;
        for (int k = 0; k < NBINS; ++k) {
            float a = (k == 0) ? 0.0f : sqrtf(fr[k] * fr[k] + fi[k] * fi[k]);
            if (a > v1)      { v3 = v2; v2 = v1; v1 = a; }
            else if (a > v2) { v3 = v2; v2 = a; }
            else if (a > v3) { v3 = a; }
        }
        int cnt = 0;
        for (int k = 0; k < NBINS; ++k) {
            float a = (k == 0) ? 0.0f : sqrtf(fr[k] * fr[k] + fi[k] * fi[k]);
            if (a >= v3 && cnt < 8) {
                float w = (k == 0 || k == 48) ? (1.0f / 96.0f) : (2.0f / 96.0f);
                selk[n * 8 + cnt] = k;
                selr[n * 8 + cnt] = w * fr[k];
                seli[n * 8 + cnt] = w * fi[k];
                cnt++;
            }
        }
        selcnt[n] = cnt;
    }
    __syncthreads();

    // ------------- Phase E: trend + season -> x_lin (reduced over n) -------------
    {
        float b0 = b0sh;
        for (int j = 0; j < 12; ++j) {
            int pidx = tid + NTHREADS * j;
            int t = pidx >> 5, n = pidx & 31;
            float xv = xs[t * XLD + n];
            // moving averages k=4,8,12 with edge-replicate padding
            #define XC(tt) xs[(((tt) < 0) ? 0 : (((tt) > 95) ? 95 : (tt))) * XLD + n]
            float s4  = XC(t - 1) + xv + XC(t + 1) + XC(t + 2);
            float s8  = s4  + XC(t - 3) + XC(t - 2) + XC(t + 3) + XC(t + 4);
            float s12 = s8  + XC(t - 5) + XC(t - 4) + XC(t + 5) + XC(t + 6);
            #undef XC
            float trend = (s4 * 0.25f + s8 * 0.125f + s12 * (1.0f / 12.0f)) * (1.0f / 3.0f);
            // seasonality from selected bins
            float season = 0.0f;
            int cnt = selcnt[n];
            for (int q = 0; q < cnt; ++q) {
                int k = selk[n * 8 + q];
                int m = (t * k) % 96;
                season = fmaf(selr[n * 8 + q], ct[m], season);
                season = fmaf(seli[n * 8 + q], st[m], season);
            }
            float val = (xv + trend + season) * wst[n];
            #pragma unroll
            for (int d = 16; d >= 1; d >>= 1) val += __shfl_xor(val, d, 64);
            if ((tid & 31) == 0) xlin[t] = val + b0;
        }
    }
    __syncthreads();

    // ---------------- Phase F: gating ----------------
    if (tid < 8) {
        int e = tid & 3;
        const float* W = (tid < 4) ? (p.wg + e * 96) : (p.wn + e * 96);
        float acc = 0.0f;
        for (int t = 0; t < TT; ++t) acc = fmaf(xlin[t], W[t], acc);
        gtmp[tid] = acc + ((tid < 4) ? p.bg[e] : p.bn[e]);
    }
    __syncthreads();
    if (tid == 0) {
        float clean[4], stdv[4], noisy[4];
        #pragma unroll
        for (int e = 0; e < 4; ++e) {
            clean[e] = gtmp[e];
            float r = gtmp[4 + e];
            float sp = fmaxf(r, 0.0f) + log1pf(expf(-fabsf(r)));   // softplus
            stdv[e] = fminf(fmaxf(sp + 0.01f, 0.001f), 1000.0f);
            noisy[e] = clean[e] + p.noise[(size_t)b * 4 + e] * stdv[e];
        }
        // top-3 of 4, ties -> lower index first (strict >)
        int i1 = 0, i2 = -1;
        float v1 = -INFINITY, v2 = -INFINITY, v3 = -INFINITY;
        for (int e = 0; e < 4; ++e) if (noisy[e] > v1) { v1 = noisy[e]; i1 = e; }
        for (int e = 0; e < 4; ++e) if (e != i1 && noisy[e] > v2) { v2 = noisy[e]; i2 = e; }
        for (int e = 0; e < 4; ++e) if (e != i1 && e != i2 && noisy[e] > v3) { v3 = noisy[e]; }
        float e2 = expf(v2 - v1);
        float g1 = 1.0f / (1.0f + e2);
        float g2 = e2 * g1;
        float gates[4] = {0.0f, 0.0f, 0.0f, 0.0f};
        gates[i1] = g1; gates[i2] = g2;
        const float inv_sqrt2 = 0.7071067811865476f;
        #pragma unroll
        for (int e = 0; e < 4; ++e) {
            float thr = (noisy[e] > v3) ? v3 : v2;
            float z = (clean[e] - thr) / stdv[e];
            z = fminf(fmaxf(z, -50.0f), 50.0f);
            float pr = 0.5f * (1.0f + erff(z * inv_sqrt2));
            pr = fminf(fmaxf(pr, 0.0f), 1.0f);
            p.part[(size_t)b * 8 + e] = gates[e];
            p.part[(size_t)b * 8 + 4 + e] = pr;
            gsh[e] = gates[e];
        }
    }
    __syncthreads();

    // ---------------- Phase G: experts (only gates>0 run; exactly 2) ----------------
    float* outsh = frfi;   // alias: fr/fi dead after Phase D/E
    for (int idx = tid; idx < TT * XLD; idx += NTHREADS) outsh[idx] = 0.0f;
    __syncthreads();

    if (gsh[0] != 0.0f) { run_expert<8>(xs, outsh, wsh, 0,   960,  1920, 2048, gsh[0], tid); __syncthreads(); }
    if (gsh[1] != 0.0f) { run_expert<6>(xs, outsh, wsh, 256, 1216, 1952, 2056, gsh[1], tid); __syncthreads(); }
    if (gsh[2] != 0.0f) { run_expert<4>(xs, outsh, wsh, 448, 1408, 1984, 2062, gsh[2], tid); __syncthreads(); }
    if (gsh[3] != 0.0f) { run_expert<12>(xs, outsh, wsh, 576, 1536, 2016, 2066, gsh[3], tid); __syncthreads(); }

    float* ob = p.out + (size_t)b * (TT * TN);
    for (int idx = tid; idx < TT * TN; idx += NTHREADS)
        ob[idx] = outsh[(idx >> 5) * XLD + (idx & 31)];
}

__global__ __launch_bounds__(NTHREADS) void ams_finalize(const float* __restrict__ part,
                                                         float* __restrict__ out_loss) {
    __shared__ float red[4][8];
    float acc[8] = {0, 0, 0, 0, 0, 0, 0, 0};
    for (int r = threadIdx.x; r < TB; r += NTHREADS) {
        #pragma unroll
        for (int c = 0; c < 8; ++c) acc[c] += part[(size_t)r * 8 + c];
    }
    #pragma unroll
    for (int c = 0; c < 8; ++c) {
        #pragma unroll
        for (int d = 32; d >= 1; d >>= 1) acc[c] += __shfl_xor(acc[c], d, 64);
    }
    int wid = threadIdx.x >> 6;
    if ((threadIdx.x & 63) == 0) {
        #pragma unroll
        for (int c = 0; c < 8; ++c) red[wid][c] = acc[c];
    }
    __syncthreads();
    if (threadIdx.x == 0) {
        float imp[4], load[4];
        #pragma unroll
        for (int c = 0; c < 4; ++c) imp[c]  = red[0][c] + red[1][c] + red[2][c] + red[3][c];
        #pragma unroll
        for (int c = 0; c < 4; ++c) load[c] = red[0][4 + c] + red[1][4 + c] + red[2][4 + c] + red[3][4 + c];
        float mi = (imp[0] + imp[1] + imp[2] + imp[3]) * 0.25f;
        float vi = 0.0f;
        #pragma unroll
        for (int i = 0; i < 4; ++i) { float d = imp[i] - mi; vi += d * d; }
        vi *= (1.0f / 3.0f);
        float ml = (load[0] + load[1] + load[2] + load[3]) * 0.25f;
        float vl = 0.0f;
        #pragma unroll
        for (int i = 0; i < 4; ++i) { float d = load[i] - ml; vl += d * d; }
        vl *= (1.0f / 3.0f);
        float cvi = vi / (mi * mi + 1e-10f);
        float cvl = vl / (ml * ml + 1e-10f);
        out_loss[0] = (cvi + cvl) * 1e-4f;
    }
}

extern "C" void kernel_launch(void* const* d_in, const int* in_sizes, int n_in,
                              void* d_out, int out_size, void* d_ws, size_t ws_size,
                              hipStream_t stream) {
    Params p;
    p.x       = (const float*)d_in[0];
    p.noise   = (const float*)d_in[1];
    p.w_start = (const float*)d_in[2];
    p.b_start = (const float*)d_in[3];
    p.wg      = (const float*)d_in[4];
    p.bg      = (const float*)d_in[5];
    p.wn      = (const float*)d_in[6];
    p.bn      = (const float*)d_in[7];
    for (int i = 0; i < 16; ++i) p.ew[i] = (const float*)d_in[8 + i];
    p.out  = (float*)d_out;
    p.part = (float*)d_ws;   // 4096 * 8 floats = 128 KB of scratch

    ams_main<<<TB, NTHREADS, 0, stream>>>(p);
    ams_finalize<<<1, NTHREADS, 0, stream>>>((const float*)d_ws,
                                             (float*)d_out + (size_t)TB * TT * TN);
}

// Round 4
// 1384.904 us; speedup vs baseline: 1.4486x; 1.4486x over previous
//
#include <hip/hip_runtime.h>
#include <math.h>

#define NTHREADS 256
constexpr int TB = 4096;   // batch
constexpr int TT = 96;     // time
constexpr int TN = 32;     // channels
constexpr int NBINS = 49;  // rfft bins for T=96
constexpr int XLD = 33;    // padded LDS leading dim

struct Params {
    const float* x; const float* noise;
    const float* w_start; const float* b_start;
    const float* wg; const float* bg; const float* wn; const float* bn;
    const float* ew[16];   // e0_w1,e0_b1,e0_w2,e0_b2, e1_w1, ...
    float* out; float* part;
};

__device__ __forceinline__ float gelu_f(float v) {
    // jax.nn.gelu approximate=True (tanh form); tanh via fast exp
    float u = 0.7978845608028654f * (v + 0.044715f * v * v * v);
    float e = __expf(2.0f * u);
    float th = 1.0f - 2.0f / (e + 1.0f);
    return 0.5f * v * (1.0f + th);
}

// Fused expert: never materialize h[32]; live set = v[P] + y[P] + temps (~2P+4 regs)
template<int P>
__device__ __forceinline__ void run_expert(const float* __restrict__ xs,
        float* __restrict__ outsh, const float* __restrict__ wsh,
        int w1o, int w2o, int b1o, int b2o, float g, int tid) {
    constexpr int NTASK = (TT / P) * TN;
    for (int task = tid; task < NTASK; task += NTHREADS) {
        const int n  = task & 31;
        const int tb = task >> 5;
        float v[P], y[P];
        #pragma unroll
        for (int l = 0; l < P; ++l) {
            v[l] = xs[(tb * P + l) * XLD + n];
            y[l] = wsh[b2o + l];
        }
        #pragma unroll
        for (int j = 0; j < 32; ++j) {
            float a = wsh[b1o + j];
            #pragma unroll
            for (int l = 0; l < P; ++l) a = fmaf(v[l], wsh[w1o + l * 32 + j], a);
            float h = gelu_f(a);
            #pragma unroll
            for (int l = 0; l < P; ++l) y[l] = fmaf(h, wsh[w2o + j * P + l], y[l]);
        }
        #pragma unroll
        for (int l = 0; l < P; ++l)
            outsh[(tb * P + l) * XLD + n] += g * y[l];
    }
}

// One DFT pass tracking NB bins (k = kbase + 8*j); live regs ~6*NB + 4.
template<int NB>
__device__ __forceinline__ void dft_pass(const float* __restrict__ xs,
        const float* __restrict__ ct, const float* __restrict__ st,
        float* __restrict__ frfi, int n, int kbase) {
    float c[NB], s[NB], ar[NB], ai[NB], ck[NB], sk[NB];
    #pragma unroll
    for (int j = 0; j < NB; ++j) {
        int k = kbase + 8 * j;
        c[j] = 1.0f; s[j] = 0.0f; ar[j] = 0.0f; ai[j] = 0.0f;
        if (k < NBINS) { ck[j] = ct[k]; sk[j] = st[k]; }
        else           { ck[j] = 1.0f;  sk[j] = 0.0f; }
    }
    for (int t = 0; t < TT; ++t) {
        float xv = xs[t * XLD + n];
        #pragma unroll
        for (int j = 0; j < NB; ++j) {
            ar[j] = fmaf(xv, c[j], ar[j]);      // sum x*cos
            ai[j] = fmaf(xv, s[j], ai[j]);      // sum x*sin
            float t0 = s[j] * sk[j];
            float t1 = c[j] * sk[j];
            float cn = fmaf(c[j], ck[j], -t0);  // rotate by 2*pi*k/96
            float sn = fmaf(s[j], ck[j],  t1);
            c[j] = cn; s[j] = sn;
        }
    }
    #pragma unroll
    for (int j = 0; j < NB; ++j) {
        int k = kbase + 8 * j;
        if (k < NBINS) {
            frfi[n * 50 + k]        = ar[j];
            frfi[1600 + n * 50 + k] = ai[j];
        }
    }
}

__global__ __launch_bounds__(NTHREADS, 4) void ams_main(Params p) {
    __shared__ float xs[TT * XLD];       // x2 tile (row t stride 33)
    __shared__ float ct[96], st[96];     // twiddles cos/sin(2*pi*m/96)
    __shared__ float xlin[96];
    __shared__ float frfi[3200];         // fr[n*50+k], fi at +1600; later aliased as outsh
    __shared__ float selr[256], seli[256];
    __shared__ int   selk[256];
    __shared__ int   selcnt[32];
    __shared__ float wsh[2080];          // all expert weights
    __shared__ float wst[32];
    __shared__ float gtmp[8];            // clean[4], rn[4]
    __shared__ float gsh[4];
    __shared__ float b0sh;

    const int tid = threadIdx.x;
    const int b = blockIdx.x;

    // ---------------- Phase A: stage x, weights, twiddles ----------------
    const float* xb = p.x + (size_t)b * (TT * TN);
    for (int idx = tid; idx < TT * TN; idx += NTHREADS)
        xs[(idx >> 5) * XLD + (idx & 31)] = xb[idx];
    if (tid < 96) {
        float ang = (float)tid * 0.06544984694978735f;  // 2*pi/96
        ct[tid] = cosf(ang);
        st[tid] = sinf(ang);
    }
    {
        constexpr int PP[4]  = {8, 6, 4, 12};
        constexpr int W1O[4] = {0, 256, 448, 576};
        constexpr int W2O[4] = {960, 1216, 1408, 1536};
        constexpr int B1O[4] = {1920, 1952, 1984, 2016};
        constexpr int B2O[4] = {2048, 2056, 2062, 2066};
        #pragma unroll
        for (int i = 0; i < 4; ++i) {
            const float* w1 = p.ew[4 * i + 0];
            const float* b1 = p.ew[4 * i + 1];
            const float* w2 = p.ew[4 * i + 2];
            const float* b2 = p.ew[4 * i + 3];
            for (int j = tid; j < PP[i] * 32; j += NTHREADS) wsh[W1O[i] + j] = w1[j];
            for (int j = tid; j < 32;         j += NTHREADS) wsh[B1O[i] + j] = b1[j];
            for (int j = tid; j < PP[i] * 32; j += NTHREADS) wsh[W2O[i] + j] = w2[j];
            for (int j = tid; j < PP[i];      j += NTHREADS) wsh[B2O[i] + j] = b2[j];
        }
    }
    if (tid < 32) wst[tid] = p.w_start[tid];
    if (tid == 0) b0sh = p.b_start[0];
    __syncthreads();

    // ---------------- Phase C: real DFT via register rotation, 2 passes ----------------
    // thread -> (n = tid>>3, kslot = tid&7); pass A: k=kslot+{0,8,16,24}, pass B: k=kslot+{32,40,48}
    {
        const int n = tid >> 3;
        const int kslot = tid & 7;
        dft_pass<4>(xs, ct, st, frfi, n, kslot);
        dft_pass<3>(xs, ct, st, frfi, n, kslot + 32);
    }
    __syncthreads();

    // ---------------- Phase D: per-series top-3 amplitude selection ----------------
    if (tid < 32) {
        const int n = tid;
        const float* fr = &frfi[n * 50];
        const float* fi = &frfi[1600 + n * 50];
        float v1 = -1.0f, v2 = -1.0f, v3 = -1.0f;
        for (int k = 0; k < NBINS; ++k) {
            float a = (k == 0) ? 0.0f : sqrtf(fr[k] * fr[k] + fi[k] * fi[k]);
            if (a > v1)      { v3 = v2; v2 = v1; v1 = a; }
            else if (a > v2) { v3 = v2; v2 = a; }
            else if (a > v3) { v3 = a; }
        }
        int cnt = 0;
        for (int k = 0; k < NBINS; ++k) {
            float a = (k == 0) ? 0.0f : sqrtf(fr[k] * fr[k] + fi[k] * fi[k]);
            if (a >= v3 && cnt < 8) {
                float w = (k == 0 || k == 48) ? (1.0f / 96.0f) : (2.0f / 96.0f);
                selk[n * 8 + cnt] = k;
                selr[n * 8 + cnt] = w * fr[k];
                seli[n * 8 + cnt] = w * fi[k];
                cnt++;
            }
        }
        selcnt[n] = cnt;
    }
    __syncthreads();

    // ------------- Phase E: trend + season -> x_lin (reduced over n) -------------
    {
        float b0 = b0sh;
        for (int j = 0; j < 12; ++j) {
            int pidx = tid + NTHREADS * j;
            int t = pidx >> 5, n = pidx & 31;
            float xv = xs[t * XLD + n];
            // moving averages k=4,8,12 with edge-replicate padding
            #define XC(tt) xs[(((tt) < 0) ? 0 : (((tt) > 95) ? 95 : (tt))) * XLD + n]
            float s4  = XC(t - 1) + xv + XC(t + 1) + XC(t + 2);
            float s8  = s4  + XC(t - 3) + XC(t - 2) + XC(t + 3) + XC(t + 4);
            float s12 = s8  + XC(t - 5) + XC(t - 4) + XC(t + 5) + XC(t + 6);
            #undef XC
            float trend = (s4 * 0.25f + s8 * 0.125f + s12 * (1.0f / 12.0f)) * (1.0f / 3.0f);
            // seasonality from selected bins
            float season = 0.0f;
            int cnt = selcnt[n];
            for (int q = 0; q < cnt; ++q) {
                int k = selk[n * 8 + q];
                int m = (t * k) % 96;
                season = fmaf(selr[n * 8 + q], ct[m], season);
                season = fmaf(seli[n * 8 + q], st[m], season);
            }
            float val = (xv + trend + season) * wst[n];
            #pragma unroll
            for (int d = 16; d >= 1; d >>= 1) val += __shfl_xor(val, d, 64);
            if ((tid & 31) == 0) xlin[t] = val + b0;
        }
    }
    __syncthreads();

    // ---------------- Phase F: gating ----------------
    if (tid < 8) {
        int e = tid & 3;
        const float* W = (tid < 4) ? (p.wg + e * 96) : (p.wn + e * 96);
        float acc = 0.0f;
        for (int t = 0; t < TT; ++t) acc = fmaf(xlin[t], W[t], acc);
        gtmp[tid] = acc + ((tid < 4) ? p.bg[e] : p.bn[e]);
    }
    __syncthreads();
    if (tid == 0) {
        float clean[4], stdv[4], noisy[4];
        #pragma unroll
        for (int e = 0; e < 4; ++e) {
            clean[e] = gtmp[e];
            float r = gtmp[4 + e];
            float sp = fmaxf(r, 0.0f) + log1pf(expf(-fabsf(r)));   // softplus
            stdv[e] = fminf(fmaxf(sp + 0.01f, 0.001f), 1000.0f);
            noisy[e] = clean[e] + p.noise[(size_t)b * 4 + e] * stdv[e];
        }
        // top-3 of 4, ties -> lower index first (strict >)
        int i1 = 0, i2 = -1;
        float v1 = -INFINITY, v2 = -INFINITY, v3 = -INFINITY;
        for (int e = 0; e < 4; ++e) if (noisy[e] > v1) { v1 = noisy[e]; i1 = e; }
        for (int e = 0; e < 4; ++e) if (e != i1 && noisy[e] > v2) { v2 = noisy[e]; i2 = e; }
        for (int e = 0; e < 4; ++e) if (e != i1 && e != i2 && noisy[e] > v3) { v3 = noisy[e]; }
        float e2 = expf(v2 - v1);
        float g1 = 1.0f / (1.0f + e2);
        float g2 = e2 * g1;
        float gates[4] = {0.0f, 0.0f, 0.0f, 0.0f};
        gates[i1] = g1; gates[i2] = g2;
        const float inv_sqrt2 = 0.7071067811865476f;
        #pragma unroll
        for (int e = 0; e < 4; ++e) {
            float thr = (noisy[e] > v3) ? v3 : v2;
            float z = (clean[e] - thr) / stdv[e];
            z = fminf(fmaxf(z, -50.0f), 50.0f);
            float pr = 0.5f * (1.0f + erff(z * inv_sqrt2));
            pr = fminf(fmaxf(pr, 0.0f), 1.0f);
            p.part[(size_t)b * 8 + e] = gates[e];
            p.part[(size_t)b * 8 + 4 + e] = pr;
            gsh[e] = gates[e];
        }
    }
    __syncthreads();

    // ---------------- Phase G: experts (only gates>0 run; exactly 2) ----------------
    float* outsh = frfi;   // alias: fr/fi dead after Phase D/E
    for (int idx = tid; idx < TT * XLD; idx += NTHREADS) outsh[idx] = 0.0f;
    __syncthreads();

    if (gsh[0] != 0.0f) { run_expert<8>(xs, outsh, wsh, 0,   960,  1920, 2048, gsh[0], tid); __syncthreads(); }
    if (gsh[1] != 0.0f) { run_expert<6>(xs, outsh, wsh, 256, 1216, 1952, 2056, gsh[1], tid); __syncthreads(); }
    if (gsh[2] != 0.0f) { run_expert<4>(xs, outsh, wsh, 448, 1408, 1984, 2062, gsh[2], tid); __syncthreads(); }
    if (gsh[3] != 0.0f) { run_expert<12>(xs, outsh, wsh, 576, 1536, 2016, 2066, gsh[3], tid); __syncthreads(); }

    float* ob = p.out + (size_t)b * (TT * TN);
    for (int idx = tid; idx < TT * TN; idx += NTHREADS)
        ob[idx] = outsh[(idx >> 5) * XLD + (idx & 31)];
}

__global__ __launch_bounds__(NTHREADS) void ams_finalize(const float* __restrict__ part,
                                                         float* __restrict__ out_loss) {
    __shared__ float red[4][8];
    float acc[8] = {0, 0, 0, 0, 0, 0, 0, 0};
    for (int r = threadIdx.x; r < TB; r += NTHREADS) {
        #pragma unroll
        for (int c = 0; c < 8; ++c) acc[c] += part[(size_t)r * 8 + c];
    }
    #pragma unroll
    for (int c = 0; c < 8; ++c) {
        #pragma unroll
        for (int d = 32; d >= 1; d >>= 1) acc[c] += __shfl_xor(acc[c], d, 64);
    }
    int wid = threadIdx.x >> 6;
    if ((threadIdx.x & 63) == 0) {
        #pragma unroll
        for (int c = 0; c < 8; ++c) red[wid][c] = acc[c];
    }
    __syncthreads();
    if (threadIdx.x == 0) {
        float imp[4], load[4];
        #pragma unroll
        for (int c = 0; c < 4; ++c) imp[c]  = red[0][c] + red[1][c] + red[2][c] + red[3][c];
        #pragma unroll
        for (int c = 0; c < 4; ++c) load[c] = red[0][4 + c] + red[1][4 + c] + red[2][4 + c] + red[3][4 + c];
        float mi = (imp[0] + imp[1] + imp[2] + imp[3]) * 0.25f;
        float vi = 0.0f;
        #pragma unroll
        for (int i = 0; i < 4; ++i) { float d = imp[i] - mi; vi += d * d; }
        vi *= (1.0f / 3.0f);
        float ml = (load[0] + load[1] + load[2] + load[3]) * 0.25f;
        float vl = 0.0f;
        #pragma unroll
        for (int i = 0; i < 4; ++i) { float d = load[i] - ml; vl += d * d; }
        vl *= (1.0f / 3.0f);
        float cvi = vi / (mi * mi + 1e-10f);
        float cvl = vl / (ml * ml + 1e-10f);
        out_loss[0] = (cvi + cvl) * 1e-4f;
    }
}

extern "C" void kernel_launch(void* const* d_in, const int* in_sizes, int n_in,
                              void* d_out, int out_size, void* d_ws, size_t ws_size,
                              hipStream_t stream) {
    Params p;
    p.x       = (const float*)d_in[0];
    p.noise   = (const float*)d_in[1];
    p.w_start = (const float*)d_in[2];
    p.b_start = (const float*)d_in[3];
    p.wg      = (const float*)d_in[4];
    p.bg      = (const float*)d_in[5];
    p.wn      = (const float*)d_in[6];
    p.bn      = (const float*)d_in[7];
    for (int i = 0; i < 16; ++i) p.ew[i] = (const float*)d_in[8 + i];
    p.out  = (float*)d_out;
    p.part = (float*)d_ws;   // 4096 * 8 floats = 128 KB of scratch

    ams_main<<<TB, NTHREADS, 0, stream>>>(p);
    ams_finalize<<<1, NTHREADS, 0, stream>>>((const float*)d_ws,
                                             (float*)d_out + (size_t)TB * TT * TN);
}

// Round 5
// 927.549 us; speedup vs baseline: 2.1629x; 1.4931x over previous
//
#include <hip/hip_runtime.h>
#include <math.h>

#define NTHREADS 256
constexpr int TB = 4096;   // batch
constexpr int TT = 96;     // time
constexpr int TN = 32;     // channels
constexpr int NBINS = 49;  // rfft bins for T=96
constexpr int XLD = 33;    // padded LDS leading dim

struct Params {
    const float* x; const float* noise;
    const float* w_start; const float* b_start;
    const float* wg; const float* bg; const float* wn; const float* bn;
    const float* ew[16];   // e0_w1,e0_b1,e0_w2,e0_b2, e1_w1, ...
    float* out; float* part;
};

__device__ __forceinline__ float gelu_f(float v) {
    // jax.nn.gelu approximate=True (tanh form); tanh via fast exp
    float u = 0.7978845608028654f * (v + 0.044715f * v * v * v);
    float e = __expf(2.0f * u);
    float th = 1.0f - 2.0f / (e + 1.0f);
    return 0.5f * v * (1.0f + th);
}

// Fused expert: never materialize h[32]; live set = v[P] + y[P] + temps (~2P+4 regs)
template<int P>
__device__ __forceinline__ void run_expert(const float* __restrict__ xs,
        float* __restrict__ outsh, const float* __restrict__ wsh,
        int w1o, int w2o, int b1o, int b2o, float g, int tid) {
    constexpr int NTASK = (TT / P) * TN;
    for (int task = tid; task < NTASK; task += NTHREADS) {
        const int n  = task & 31;
        const int tb = task >> 5;
        float v[P], y[P];
        #pragma unroll
        for (int l = 0; l < P; ++l) {
            v[l] = xs[(tb * P + l) * XLD + n];
            y[l] = wsh[b2o + l];
        }
        #pragma unroll
        for (int j = 0; j < 32; ++j) {
            float a = wsh[b1o + j];
            #pragma unroll
            for (int l = 0; l < P; ++l) a = fmaf(v[l], wsh[w1o + l * 32 + j], a);
            float h = gelu_f(a);
            #pragma unroll
            for (int l = 0; l < P; ++l) y[l] = fmaf(h, wsh[w2o + j * P + l], y[l]);
        }
        #pragma unroll
        for (int l = 0; l < P; ++l)
            outsh[(tb * P + l) * XLD + n] += g * y[l];
    }
}

// One DFT pass tracking NB bins (k = kbase + 8*j); live regs ~6*NB + 4.
template<int NB>
__device__ __forceinline__ void dft_pass(const float* __restrict__ xs,
        const float* __restrict__ ct, const float* __restrict__ st,
        float* __restrict__ frfi, int n, int kbase) {
    float c[NB], s[NB], ar[NB], ai[NB], ck[NB], sk[NB];
    #pragma unroll
    for (int j = 0; j < NB; ++j) {
        int k = kbase + 8 * j;
        c[j] = 1.0f; s[j] = 0.0f; ar[j] = 0.0f; ai[j] = 0.0f;
        if (k < NBINS) { ck[j] = ct[k]; sk[j] = st[k]; }
        else           { ck[j] = 1.0f;  sk[j] = 0.0f; }
    }
    for (int t = 0; t < TT; ++t) {
        float xv = xs[t * XLD + n];
        #pragma unroll
        for (int j = 0; j < NB; ++j) {
            ar[j] = fmaf(xv, c[j], ar[j]);      // sum x*cos
            ai[j] = fmaf(xv, s[j], ai[j]);      // sum x*sin
            float t0 = s[j] * sk[j];
            float t1 = c[j] * sk[j];
            float cn = fmaf(c[j], ck[j], -t0);  // rotate by 2*pi*k/96
            float sn = fmaf(s[j], ck[j],  t1);
            c[j] = cn; s[j] = sn;
        }
    }
    #pragma unroll
    for (int j = 0; j < NB; ++j) {
        int k = kbase + 8 * j;
        if (k < NBINS) {
            frfi[n * 50 + k]        = ar[j];
            frfi[1600 + n * 50 + k] = ai[j];
        }
    }
}

__global__ __launch_bounds__(NTHREADS) void ams_main(Params p) {
    __shared__ float xs[TT * XLD];       // x2 tile (row t stride 33)
    __shared__ float ct[96], st[96];     // twiddles cos/sin(2*pi*m/96)
    __shared__ float xlin[96];
    __shared__ float frfi[3200];         // fr[n*50+k], fi at +1600; later aliased as outsh
    __shared__ float selr[256], seli[256];
    __shared__ int   selk[256];
    __shared__ int   selcnt[32];
    __shared__ float wsh[2080];          // all expert weights
    __shared__ float wst[32];
    __shared__ float gtmp[8];            // clean[4], rn[4]
    __shared__ float gsh[4];
    __shared__ float b0sh;

    const int tid = threadIdx.x;
    const int b = blockIdx.x;

    // ---------------- Phase A: stage x, weights, twiddles ----------------
    const float* xb = p.x + (size_t)b * (TT * TN);
    for (int idx = tid; idx < TT * TN; idx += NTHREADS)
        xs[(idx >> 5) * XLD + (idx & 31)] = xb[idx];
    if (tid < 96) {
        float ang = (float)tid * 0.06544984694978735f;  // 2*pi/96
        ct[tid] = cosf(ang);
        st[tid] = sinf(ang);
    }
    {
        constexpr int PP[4]  = {8, 6, 4, 12};
        constexpr int W1O[4] = {0, 256, 448, 576};
        constexpr int W2O[4] = {960, 1216, 1408, 1536};
        constexpr int B1O[4] = {1920, 1952, 1984, 2016};
        constexpr int B2O[4] = {2048, 2056, 2062, 2066};
        #pragma unroll
        for (int i = 0; i < 4; ++i) {
            const float* w1 = p.ew[4 * i + 0];
            const float* b1 = p.ew[4 * i + 1];
            const float* w2 = p.ew[4 * i + 2];
            const float* b2 = p.ew[4 * i + 3];
            for (int j = tid; j < PP[i] * 32; j += NTHREADS) wsh[W1O[i] + j] = w1[j];
            for (int j = tid; j < 32;         j += NTHREADS) wsh[B1O[i] + j] = b1[j];
            for (int j = tid; j < PP[i] * 32; j += NTHREADS) wsh[W2O[i] + j] = w2[j];
            for (int j = tid; j < PP[i];      j += NTHREADS) wsh[B2O[i] + j] = b2[j];
        }
    }
    if (tid < 32) wst[tid] = p.w_start[tid];
    if (tid == 0) b0sh = p.b_start[0];
    __syncthreads();

    // ---------------- Phase C: real DFT via register rotation, 2 passes ----------------
    // thread -> (n = tid>>3, kslot = tid&7); pass A: k=kslot+{0,8,16,24}, pass B: k=kslot+{32,40,48}
    {
        const int n = tid >> 3;
        const int kslot = tid & 7;
        dft_pass<4>(xs, ct, st, frfi, n, kslot);
        dft_pass<3>(xs, ct, st, frfi, n, kslot + 32);
    }
    __syncthreads();

    // ---------------- Phase D: per-series top-3 amplitude selection ----------------
    if (tid < 32) {
        const int n = tid;
        const float* fr = &frfi[n * 50];
        const float* fi = &frfi[1600 + n * 50];
        float v1 = -1.0f, v2 = -1.0f, v3 = -1.0f;
        for (int k = 0; k < NBINS; ++k) {
            float a = (k == 0) ? 0.0f : sqrtf(fr[k] * fr[k] + fi[k] * fi[k]);
            if (a > v1)      { v3 = v2; v2 = v1; v1 = a; }
            else if (a > v2) { v3 = v2; v2 = a; }
            else if (a > v3) { v3 = a; }
        }
        int cnt = 0;
        for (int k = 0; k < NBINS; ++k) {
            float a = (k == 0) ? 0.0f : sqrtf(fr[k] * fr[k] + fi[k] * fi[k]);
            if (a >= v3 && cnt < 8) {
                float w = (k == 0 || k == 48) ? (1.0f / 96.0f) : (2.0f / 96.0f);
                selk[n * 8 + cnt] = k;
                selr[n * 8 + cnt] = w * fr[k];
                seli[n * 8 + cnt] = w * fi[k];
                cnt++;
            }
        }
        selcnt[n] = cnt;
    }
    __syncthreads();

    // ------------- Phase E: trend + season -> x_lin (reduced over n) -------------
    {
        float b0 = b0sh;
        for (int j = 0; j < 12; ++j) {
            int pidx = tid + NTHREADS * j;
            int t = pidx >> 5, n = pidx & 31;
            float xv = xs[t * XLD + n];
            // moving averages k=4,8,12 with edge-replicate padding
            #define XC(tt) xs[(((tt) < 0) ? 0 : (((tt) > 95) ? 95 : (tt))) * XLD + n]
            float s4  = XC(t - 1) + xv + XC(t + 1) + XC(t + 2);
            float s8  = s4  + XC(t - 3) + XC(t - 2) + XC(t + 3) + XC(t + 4);
            float s12 = s8  + XC(t - 5) + XC(t - 4) + XC(t + 5) + XC(t + 6);
            #undef XC
            float trend = (s4 * 0.25f + s8 * 0.125f + s12 * (1.0f / 12.0f)) * (1.0f / 3.0f);
            // seasonality from selected bins
            float season = 0.0f;
            int cnt = selcnt[n];
            for (int q = 0; q < cnt; ++q) {
                int k = selk[n * 8 + q];
                int m = (t * k) % 96;
                season = fmaf(selr[n * 8 + q], ct[m], season);
                season = fmaf(seli[n * 8 + q], st[m], season);
            }
            float val = (xv + trend + season) * wst[n];
            #pragma unroll
            for (int d = 16; d >= 1; d >>= 1) val += __shfl_xor(val, d, 64);
            if ((tid & 31) == 0) xlin[t] = val + b0;
        }
    }
    __syncthreads();

    // ---------------- Phase F: gating ----------------
    if (tid < 8) {
        int e = tid & 3;
        const float* W = (tid < 4) ? (p.wg + e * 96) : (p.wn + e * 96);
        float acc = 0.0f;
        for (int t = 0; t < TT; ++t) acc = fmaf(xlin[t], W[t], acc);
        gtmp[tid] = acc + ((tid < 4) ? p.bg[e] : p.bn[e]);
    }
    __syncthreads();
    if (tid == 0) {
        float clean[4], stdv[4], noisy[4];
        #pragma unroll
        for (int e = 0; e < 4; ++e) {
            clean[e] = gtmp[e];
            float r = gtmp[4 + e];
            float sp = fmaxf(r, 0.0f) + log1pf(expf(-fabsf(r)));   // softplus
            stdv[e] = fminf(fmaxf(sp + 0.01f, 0.001f), 1000.0f);
            noisy[e] = clean[e] + p.noise[(size_t)b * 4 + e] * stdv[e];
        }
        // top-3 of 4, ties -> lower index first (strict >)
        int i1 = 0, i2 = -1;
        float v1 = -INFINITY, v2 = -INFINITY, v3 = -INFINITY;
        for (int e = 0; e < 4; ++e) if (noisy[e] > v1) { v1 = noisy[e]; i1 = e; }
        for (int e = 0; e < 4; ++e) if (e != i1 && noisy[e] > v2) { v2 = noisy[e]; i2 = e; }
        for (int e = 0; e < 4; ++e) if (e != i1 && e != i2 && noisy[e] > v3) { v3 = noisy[e]; }
        float e2 = expf(v2 - v1);
        float g1 = 1.0f / (1.0f + e2);
        float g2 = e2 * g1;
        float gates[4] = {0.0f, 0.0f, 0.0f, 0.0f};
        gates[i1] = g1; gates[i2] = g2;
        const float inv_sqrt2 = 0.7071067811865476f;
        #pragma unroll
        for (int e = 0; e < 4; ++e) {
            float thr = (noisy[e] > v3) ? v3 : v2;
            float z = (clean[e] - thr) / stdv[e];
            z = fminf(fmaxf(z, -50.0f), 50.0f);
            float pr = 0.5f * (1.0f + erff(z * inv_sqrt2));
            pr = fminf(fmaxf(pr, 0.0f), 1.0f);
            p.part[(size_t)b * 8 + e] = gates[e];
            p.part[(size_t)b * 8 + 4 + e] = pr;
            gsh[e] = gates[e];
        }
    }
    __syncthreads();

    // ---------------- Phase G: experts (only gates>0 run; exactly 2) ----------------
    float* outsh = frfi;   // alias: fr/fi dead after Phase D/E
    for (int idx = tid; idx < TT * XLD; idx += NTHREADS) outsh[idx] = 0.0f;
    __syncthreads();

    if (gsh[0] != 0.0f) { run_expert<8>(xs, outsh, wsh, 0,   960,  1920, 2048, gsh[0], tid); __syncthreads(); }
    if (gsh[1] != 0.0f) { run_expert<6>(xs, outsh, wsh, 256, 1216, 1952, 2056, gsh[1], tid); __syncthreads(); }
    if (gsh[2] != 0.0f) { run_expert<4>(xs, outsh, wsh, 448, 1408, 1984, 2062, gsh[2], tid); __syncthreads(); }
    if (gsh[3] != 0.0f) { run_expert<12>(xs, outsh, wsh, 576, 1536, 2016, 2066, gsh[3], tid); __syncthreads(); }

    float* ob = p.out + (size_t)b * (TT * TN);
    for (int idx = tid; idx < TT * TN; idx += NTHREADS)
        ob[idx] = outsh[(idx >> 5) * XLD + (idx & 31)];
}

__global__ __launch_bounds__(NTHREADS) void ams_finalize(const float* __restrict__ part,
                                                         float* __restrict__ out_loss) {
    __shared__ float red[4][8];
    float acc[8] = {0, 0, 0, 0, 0, 0, 0, 0};
    for (int r = threadIdx.x; r < TB; r += NTHREADS) {
        #pragma unroll
        for (int c = 0; c < 8; ++c) acc[c] += part[(size_t)r * 8 + c];
    }
    #pragma unroll
    for (int c = 0; c < 8; ++c) {
        #pragma unroll
        for (int d = 32; d >= 1; d >>= 1) acc[c] += __shfl_xor(acc[c], d, 64);
    }
    int wid = threadIdx.x >> 6;
    if ((threadIdx.x & 63) == 0) {
        #pragma unroll
        for (int c = 0; c < 8; ++c) red[wid][c] = acc[c];
    }
    __syncthreads();
    if (threadIdx.x == 0) {
        float imp[4], load[4];
        #pragma unroll
        for (int c = 0; c < 4; ++c) imp[c]  = red[0][c] + red[1][c] + red[2][c] + red[3][c];
        #pragma unroll
        for (int c = 0; c < 4; ++c) load[c] = red[0][4 + c] + red[1][4 + c] + red[2][4 + c] + red[3][4 + c];
        float mi = (imp[0] + imp[1] + imp[2] + imp[3]) * 0.25f;
        float vi = 0.0f;
        #pragma unroll
        for (int i = 0; i < 4; ++i) { float d = imp[i] - mi; vi += d * d; }
        vi *= (1.0f / 3.0f);
        float ml = (load[0] + load[1] + load[2] + load[3]) * 0.25f;
        float vl = 0.0f;
        #pragma unroll
        for (int i = 0; i < 4; ++i) { float d = load[i] - ml; vl += d * d; }
        vl *= (1.0f / 3.0f);
        float cvi = vi / (mi * mi + 1e-10f);
        float cvl = vl / (ml * ml + 1e-10f);
        out_loss[0] = (cvi + cvl) * 1e-4f;
    }
}

extern "C" void kernel_launch(void* const* d_in, const int* in_sizes, int n_in,
                              void* d_out, int out_size, void* d_ws, size_t ws_size,
                              hipStream_t stream) {
    Params p;
    p.x       = (const float*)d_in[0];
    p.noise   = (const float*)d_in[1];
    p.w_start = (const float*)d_in[2];
    p.b_start = (const float*)d_in[3];
    p.wg      = (const float*)d_in[4];
    p.bg      = (const float*)d_in[5];
    p.wn      = (const float*)d_in[6];
    p.bn      = (const float*)d_in[7];
    for (int i = 0; i < 16; ++i) p.ew[i] = (const float*)d_in[8 + i];
    p.out  = (float*)d_out;
    p.part = (float*)d_ws;   // 4096 * 8 floats = 128 KB of scratch

    ams_main<<<TB, NTHREADS, 0, stream>>>(p);
    ams_finalize<<<1, NTHREADS, 0, stream>>>((const float*)d_ws,
                                             (float*)d_out + (size_t)TB * TT * TN);
}

// Round 6
// 342.102 us; speedup vs baseline: 5.8643x; 2.7113x over previous
//
#include <hip/hip_runtime.h>
#include <math.h>

#define NTHREADS 256
constexpr int TB = 4096;   // batch
constexpr int TT = 96;     // time
constexpr int TN = 32;     // channels
constexpr int NBINS = 49;  // rfft bins for T=96
constexpr int XLD = 33;    // padded LDS leading dim

struct Params {
    const float* x; const float* noise;
    const float* w_start; const float* b_start;
    const float* wg; const float* bg; const float* wn; const float* bn;
    const float* ew[16];   // e0_w1,e0_b1,e0_w2,e0_b2, e1_w1, ...
    float* out; float* part;
};

__device__ __forceinline__ float gelu_f(float v) {
    // jax.nn.gelu approximate=True (tanh form); tanh via fast exp
    float u = 0.7978845608028654f * (v + 0.044715f * v * v * v);
    float e = __expf(2.0f * u);
    float th = 1.0f - 2.0f / (e + 1.0f);
    return 0.5f * v * (1.0f + th);
}

// Fused expert: never materialize h[32]; live set = v[P] + y[P] + temps (~2P+4 regs)
template<int P>
__device__ __forceinline__ void run_expert(const float* __restrict__ xs,
        float* __restrict__ outsh, const float* __restrict__ wsh,
        int w1o, int w2o, int b1o, int b2o, float g, int tid) {
    constexpr int NTASK = (TT / P) * TN;
    #pragma unroll 1
    for (int task = tid; task < NTASK; task += NTHREADS) {
        const int n  = task & 31;
        const int tb = task >> 5;
        float v[P], y[P];
        #pragma unroll
        for (int l = 0; l < P; ++l) {
            v[l] = xs[(tb * P + l) * XLD + n];
            y[l] = wsh[b2o + l];
        }
        #pragma unroll 4
        for (int j = 0; j < 32; ++j) {
            float a = wsh[b1o + j];
            #pragma unroll
            for (int l = 0; l < P; ++l) a = fmaf(v[l], wsh[w1o + l * 32 + j], a);
            float h = gelu_f(a);
            #pragma unroll
            for (int l = 0; l < P; ++l) y[l] = fmaf(h, wsh[w2o + j * P + l], y[l]);
        }
        #pragma unroll
        for (int l = 0; l < P; ++l)
            outsh[(tb * P + l) * XLD + n] += g * y[l];
    }
}

// One DFT pass tracking NB bins (k = kbase + 8*j); live regs ~6*NB + 4.
template<int NB>
__device__ __forceinline__ void dft_pass(const float* __restrict__ xs,
        const float* __restrict__ ct, const float* __restrict__ st,
        float* __restrict__ frfi, int n, int kbase) {
    float c[NB], s[NB], ar[NB], ai[NB], ck[NB], sk[NB];
    #pragma unroll
    for (int j = 0; j < NB; ++j) {
        int k = kbase + 8 * j;
        c[j] = 1.0f; s[j] = 0.0f; ar[j] = 0.0f; ai[j] = 0.0f;
        if (k < NBINS) { ck[j] = ct[k]; sk[j] = st[k]; }
        else           { ck[j] = 1.0f;  sk[j] = 0.0f; }
    }
    #pragma unroll 2
    for (int t = 0; t < TT; ++t) {
        float xv = xs[t * XLD + n];
        #pragma unroll
        for (int j = 0; j < NB; ++j) {
            ar[j] = fmaf(xv, c[j], ar[j]);      // sum x*cos
            ai[j] = fmaf(xv, s[j], ai[j]);      // sum x*sin
            float t0 = s[j] * sk[j];
            float t1 = c[j] * sk[j];
            float cn = fmaf(c[j], ck[j], -t0);  // rotate by 2*pi*k/96
            float sn = fmaf(s[j], ck[j],  t1);
            c[j] = cn; s[j] = sn;
        }
    }
    #pragma unroll
    for (int j = 0; j < NB; ++j) {
        int k = kbase + 8 * j;
        if (k < NBINS) {
            frfi[n * 50 + k]        = ar[j];
            frfi[1600 + n * 50 + k] = ai[j];
        }
    }
}

__global__ __launch_bounds__(NTHREADS) void ams_main(Params p) {
    __shared__ float xs[TT * XLD];       // x2 tile (row t stride 33)
    __shared__ float ct[96], st[96];     // twiddles cos/sin(2*pi*m/96)
    __shared__ float xlin[96];
    __shared__ float frfi[3200];         // fr[n*50+k], fi at +1600; later aliased as outsh
    __shared__ float selr[256], seli[256];
    __shared__ int   selk[256];
    __shared__ int   selcnt[32];
    __shared__ float wsh[2080];          // all expert weights
    __shared__ float wst[32];
    __shared__ float gtmp[8];            // clean[4], rn[4]
    __shared__ float gsh[4];
    __shared__ float b0sh;

    const int tid = threadIdx.x;
    const int b = blockIdx.x;

    // ---------------- Phase A: stage x, weights, twiddles ----------------
    const float* xb = p.x + (size_t)b * (TT * TN);
    #pragma unroll 1
    for (int idx = tid; idx < TT * TN; idx += NTHREADS)
        xs[(idx >> 5) * XLD + (idx & 31)] = xb[idx];
    if (tid < 96) {
        float ang = (float)tid * 0.06544984694978735f;  // 2*pi/96
        ct[tid] = cosf(ang);
        st[tid] = sinf(ang);
    }
    {
        constexpr int PP[4]  = {8, 6, 4, 12};
        constexpr int W1O[4] = {0, 256, 448, 576};
        constexpr int W2O[4] = {960, 1216, 1408, 1536};
        constexpr int B1O[4] = {1920, 1952, 1984, 2016};
        constexpr int B2O[4] = {2048, 2056, 2062, 2066};
        #pragma unroll 1
        for (int i = 0; i < 4; ++i) {
            const float* w1 = p.ew[4 * i + 0];
            const float* b1 = p.ew[4 * i + 1];
            const float* w2 = p.ew[4 * i + 2];
            const float* b2 = p.ew[4 * i + 3];
            #pragma unroll 1
            for (int j = tid; j < PP[i] * 32; j += NTHREADS) wsh[W1O[i] + j] = w1[j];
            if (tid < 32) wsh[B1O[i] + tid] = b1[tid];
            #pragma unroll 1
            for (int j = tid; j < PP[i] * 32; j += NTHREADS) wsh[W2O[i] + j] = w2[j];
            if (tid < PP[i]) wsh[B2O[i] + tid] = b2[tid];
        }
    }
    if (tid < 32) wst[tid] = p.w_start[tid];
    if (tid == 0) b0sh = p.b_start[0];
    __syncthreads();

    // ---------------- Phase C: real DFT via register rotation, 2 passes ----------------
    // thread -> (n = tid>>3, kslot = tid&7); pass A: k=kslot+{0,8,16,24}, pass B: k=kslot+{32,40,48}
    {
        const int n = tid >> 3;
        const int kslot = tid & 7;
        dft_pass<4>(xs, ct, st, frfi, n, kslot);
        dft_pass<3>(xs, ct, st, frfi, n, kslot + 32);
    }
    __syncthreads();

    // ---------------- Phase D: per-series top-3 amplitude selection ----------------
    if (tid < 32) {
        const int n = tid;
        const float* fr = &frfi[n * 50];
        const float* fi = &frfi[1600 + n * 50];
        float v1 = -1.0f, v2 = -1.0f, v3 = -1.0f;
        #pragma unroll 1
        for (int k = 0; k < NBINS; ++k) {
            float a = (k == 0) ? 0.0f : sqrtf(fr[k] * fr[k] + fi[k] * fi[k]);
            if (a > v1)      { v3 = v2; v2 = v1; v1 = a; }
            else if (a > v2) { v3 = v2; v2 = a; }
            else if (a > v3) { v3 = a; }
        }
        int cnt = 0;
        #pragma unroll 1
        for (int k = 0; k < NBINS; ++k) {
            float a = (k == 0) ? 0.0f : sqrtf(fr[k] * fr[k] + fi[k] * fi[k]);
            if (a >= v3 && cnt < 8) {
                float w = (k == 0 || k == 48) ? (1.0f / 96.0f) : (2.0f / 96.0f);
                selk[n * 8 + cnt] = k;
                selr[n * 8 + cnt] = w * fr[k];
                seli[n * 8 + cnt] = w * fi[k];
                cnt++;
            }
        }
        selcnt[n] = cnt;
    }
    __syncthreads();

    // ------------- Phase E: trend + season -> x_lin (reduced over n) -------------
    {
        float b0 = b0sh;
        #pragma unroll 1
        for (int j = 0; j < 12; ++j) {
            int pidx = tid + NTHREADS * j;
            int t = pidx >> 5, n = pidx & 31;
            float xv = xs[t * XLD + n];
            // moving averages k=4,8,12 with edge-replicate padding
            #define XC(tt) xs[(((tt) < 0) ? 0 : (((tt) > 95) ? 95 : (tt))) * XLD + n]
            float s4  = XC(t - 1) + xv + XC(t + 1) + XC(t + 2);
            float s8  = s4  + XC(t - 3) + XC(t - 2) + XC(t + 3) + XC(t + 4);
            float s12 = s8  + XC(t - 5) + XC(t - 4) + XC(t + 5) + XC(t + 6);
            #undef XC
            float trend = (s4 * 0.25f + s8 * 0.125f + s12 * (1.0f / 12.0f)) * (1.0f / 3.0f);
            // seasonality from selected bins
            float season = 0.0f;
            int cnt = selcnt[n];
            #pragma unroll 1
            for (int q = 0; q < cnt; ++q) {
                int k = selk[n * 8 + q];
                int m = (t * k) % 96;
                season = fmaf(selr[n * 8 + q], ct[m], season);
                season = fmaf(seli[n * 8 + q], st[m], season);
            }
            float val = (xv + trend + season) * wst[n];
            #pragma unroll
            for (int d = 16; d >= 1; d >>= 1) val += __shfl_xor(val, d, 64);
            if ((tid & 31) == 0) xlin[t] = val + b0;
        }
    }
    __syncthreads();

    // ---------------- Phase F: gating ----------------
    if (tid < 8) {
        int e = tid & 3;
        const float* W = (tid < 4) ? (p.wg + e * 96) : (p.wn + e * 96);
        float acc = 0.0f;
        #pragma unroll 1
        for (int t = 0; t < TT; ++t) acc = fmaf(xlin[t], W[t], acc);
        gtmp[tid] = acc + ((tid < 4) ? p.bg[e] : p.bn[e]);
    }
    __syncthreads();
    if (tid == 0) {
        float clean[4], stdv[4], noisy[4];
        #pragma unroll
        for (int e = 0; e < 4; ++e) {
            clean[e] = gtmp[e];
            float r = gtmp[4 + e];
            float sp = fmaxf(r, 0.0f) + log1pf(expf(-fabsf(r)));   // softplus
            stdv[e] = fminf(fmaxf(sp + 0.01f, 0.001f), 1000.0f);
            noisy[e] = clean[e] + p.noise[(size_t)b * 4 + e] * stdv[e];
        }
        // top-3 of 4, ties -> lower index first (strict >)
        int i1 = 0, i2 = -1;
        float v1 = -INFINITY, v2 = -INFINITY, v3 = -INFINITY;
        for (int e = 0; e < 4; ++e) if (noisy[e] > v1) { v1 = noisy[e]; i1 = e; }
        for (int e = 0; e < 4; ++e) if (e != i1 && noisy[e] > v2) { v2 = noisy[e]; i2 = e; }
        for (int e = 0; e < 4; ++e) if (e != i1 && e != i2 && noisy[e] > v3) { v3 = noisy[e]; }
        float e2 = expf(v2 - v1);
        float g1 = 1.0f / (1.0f + e2);
        float g2 = e2 * g1;
        float gates[4] = {0.0f, 0.0f, 0.0f, 0.0f};
        gates[i1] = g1; gates[i2] = g2;
        const float inv_sqrt2 = 0.7071067811865476f;
        #pragma unroll
        for (int e = 0; e < 4; ++e) {
            float thr = (noisy[e] > v3) ? v3 : v2;
            float z = (clean[e] - thr) / stdv[e];
            z = fminf(fmaxf(z, -50.0f), 50.0f);
            float pr = 0.5f * (1.0f + erff(z * inv_sqrt2));
            pr = fminf(fmaxf(pr, 0.0f), 1.0f);
            p.part[(size_t)b * 8 + e] = gates[e];
            p.part[(size_t)b * 8 + 4 + e] = pr;
            gsh[e] = gates[e];
        }
    }
    __syncthreads();

    // ---------------- Phase G: experts (only gates>0 run; exactly 2) ----------------
    float* outsh = frfi;   // alias: fr/fi dead after Phase D/E
    #pragma unroll 1
    for (int idx = tid; idx < TT * XLD; idx += NTHREADS) outsh[idx] = 0.0f;
    __syncthreads();

    if (gsh[0] != 0.0f) { run_expert<8>(xs, outsh, wsh, 0,   960,  1920, 2048, gsh[0], tid); __syncthreads(); }
    if (gsh[1] != 0.0f) { run_expert<6>(xs, outsh, wsh, 256, 1216, 1952, 2056, gsh[1], tid); __syncthreads(); }
    if (gsh[2] != 0.0f) { run_expert<4>(xs, outsh, wsh, 448, 1408, 1984, 2062, gsh[2], tid); __syncthreads(); }
    if (gsh[3] != 0.0f) { run_expert<12>(xs, outsh, wsh, 576, 1536, 2016, 2066, gsh[3], tid); __syncthreads(); }

    float* ob = p.out + (size_t)b * (TT * TN);
    #pragma unroll 1
    for (int idx = tid; idx < TT * TN; idx += NTHREADS)
        ob[idx] = outsh[(idx >> 5) * XLD + (idx & 31)];
}

__global__ __launch_bounds__(NTHREADS) void ams_finalize(const float* __restrict__ part,
                                                         float* __restrict__ out_loss) {
    __shared__ float red[4][8];
    float acc[8] = {0, 0, 0, 0, 0, 0, 0, 0};
    #pragma unroll 1
    for (int r = threadIdx.x; r < TB; r += NTHREADS) {
        #pragma unroll
        for (int c = 0; c < 8; ++c) acc[c] += part[(size_t)r * 8 + c];
    }
    #pragma unroll
    for (int c = 0; c < 8; ++c) {
        #pragma unroll
        for (int d = 32; d >= 1; d >>= 1) acc[c] += __shfl_xor(acc[c], d, 64);
    }
    int wid = threadIdx.x >> 6;
    if ((threadIdx.x & 63) == 0) {
        #pragma unroll
        for (int c = 0; c < 8; ++c) red[wid][c] = acc[c];
    }
    __syncthreads();
    if (threadIdx.x == 0) {
        float imp[4], load[4];
        #pragma unroll
        for (int c = 0; c < 4; ++c) imp[c]  = red[0][c] + red[1][c] + red[2][c] + red[3][c];
        #pragma unroll
        for (int c = 0; c < 4; ++c) load[c] = red[0][4 + c] + red[1][4 + c] + red[2][4 + c] + red[3][4 + c];
        float mi = (imp[0] + imp[1] + imp[2] + imp[3]) * 0.25f;
        float vi = 0.0f;
        #pragma unroll
        for (int i = 0; i < 4; ++i) { float d = imp[i] - mi; vi += d * d; }
        vi *= (1.0f / 3.0f);
        float ml = (load[0] + load[1] + load[2] + load[3]) * 0.25f;
        float vl = 0.0f;
        #pragma unroll
        for (int i = 0; i < 4; ++i) { float d = load[i] - ml; vl += d * d; }
        vl *= (1.0f / 3.0f);
        float cvi = vi / (mi * mi + 1e-10f);
        float cvl = vl / (ml * ml + 1e-10f);
        out_loss[0] = (cvi + cvl) * 1e-4f;
    }
}

extern "C" void kernel_launch(void* const* d_in, const int* in_sizes, int n_in,
                              void* d_out, int out_size, void* d_ws, size_t ws_size,
                              hipStream_t stream) {
    Params p;
    p.x       = (const float*)d_in[0];
    p.noise   = (const float*)d_in[1];
    p.w_start = (const float*)d_in[2];
    p.b_start = (const float*)d_in[3];
    p.wg      = (const float*)d_in[4];
    p.bg      = (const float*)d_in[5];
    p.wn      = (const float*)d_in[6];
    p.bn      = (const float*)d_in[7];
    for (int i = 0; i < 16; ++i) p.ew[i] = (const float*)d_in[8 + i];
    p.out  = (float*)d_out;
    p.part = (float*)d_ws;   // 4096 * 8 floats = 128 KB of scratch

    ams_main<<<TB, NTHREADS, 0, stream>>>(p);
    ams_finalize<<<1, NTHREADS, 0, stream>>>((const float*)d_ws,
                                             (float*)d_out + (size_t)TB * TT * TN);
}

// Round 7
// 329.083 us; speedup vs baseline: 6.0963x; 1.0396x over previous
//
#include <hip/hip_runtime.h>
#include <math.h>

#define NTHREADS 256
constexpr int TB = 4096;   // batch
constexpr int TT = 96;     // time
constexpr int TN = 32;     // channels
constexpr int XLD = 33;    // padded LDS leading dim

struct Params {
    const float* x; const float* noise;
    const float* w_start; const float* b_start;
    const float* wg; const float* bg; const float* wn; const float* bn;
    const float* ew[16];   // e0_w1,e0_b1,e0_w2,e0_b2, e1_w1, ...
    float* out; float* part;
};

__device__ __forceinline__ float gelu_f(float v) {
    // jax.nn.gelu approximate=True (tanh form); tanh via fast exp
    float u = 0.7978845608028654f * (v + 0.044715f * v * v * v);
    float e = __expf(2.0f * u);
    float th = 1.0f - 2.0f / (e + 1.0f);
    return 0.5f * v * (1.0f + th);
}

// One DFT pass tracking NB bins (k = kbase + 8*j); results stay in registers.
template<int NB>
__device__ __forceinline__ void dft_pass(const float* __restrict__ xs,
        const float* __restrict__ ct, const float* __restrict__ st,
        int n, int kbase, float (&ar)[NB], float (&ai)[NB]) {
    float c[NB], s[NB], ck[NB], sk[NB];
    #pragma unroll
    for (int j = 0; j < NB; ++j) {
        int k = kbase + 8 * j;          // k <= 55 < 96 always; invalid bins rotate harmlessly
        c[j] = 1.0f; s[j] = 0.0f; ar[j] = 0.0f; ai[j] = 0.0f;
        ck[j] = ct[k]; sk[j] = st[k];
    }
    #pragma unroll 2
    for (int t = 0; t < TT; ++t) {
        float xv = xs[t * XLD + n];
        #pragma unroll
        for (int j = 0; j < NB; ++j) {
            ar[j] = fmaf(xv, c[j], ar[j]);      // sum x*cos
            ai[j] = fmaf(xv, s[j], ai[j]);      // sum x*sin
            float t0 = s[j] * sk[j];
            float t1 = c[j] * sk[j];
            float cn = fmaf(c[j], ck[j], -t0);  // rotate by 2*pi*k/96
            float sn = fmaf(s[j], ck[j],  t1);
            c[j] = cn; s[j] = sn;
        }
    }
}

// Accumulate one patch of expert P into register chunk y[12].
// Patch rows (patch-local) [L0,L1) map to y[CB + l - L0]. Hidden uses full patch.
template<int P, int L0, int L1, int CB>
__device__ __forceinline__ void patch_acc(const float* __restrict__ xs,
        const float* __restrict__ wsh, int w1o, int w2o, int b1o, int b2o,
        int pb, int n, float g, float (&y)[12]) {
    float v[P];
    #pragma unroll
    for (int l = 0; l < P; ++l) v[l] = xs[(pb * P + l) * XLD + n];
    #pragma unroll 4
    for (int j = 0; j < 32; ++j) {
        float a = wsh[b1o + j];
        #pragma unroll
        for (int l = 0; l < P; ++l) a = fmaf(v[l], wsh[w1o + l * 32 + j], a);
        float gh = g * gelu_f(a);
        #pragma unroll
        for (int l = L0; l < L1; ++l) y[CB + l - L0] = fmaf(gh, wsh[w2o + j * P + l], y[CB + l - L0]);
    }
    #pragma unroll
    for (int l = L0; l < L1; ++l) y[CB + l - L0] = fmaf(g, wsh[b2o + l], y[CB + l - L0]);
}

__global__ __launch_bounds__(NTHREADS) void ams_main(Params p) {
    __shared__ float xs[TT * XLD];       // x2 tile (row t stride 33)  12.7 KB
    __shared__ float ct[96], st[96];     // twiddles cos/sin(2*pi*m/96)
    __shared__ float xlin[96];
    __shared__ float selr[256], seli[256];
    __shared__ int   selk[256];
    __shared__ int   selcnt[32];
    __shared__ float wsh[2080];          // all expert weights  8.3 KB
    __shared__ float wst[32];
    __shared__ float gtmp[8];            // clean[4], rn[4]
    __shared__ float gsh[4];
    __shared__ float b0sh;

    const int tid = threadIdx.x;
    const int b = blockIdx.x;

    // ---------------- Phase A: stage x, weights, twiddles ----------------
    const float* xb = p.x + (size_t)b * (TT * TN);
    #pragma unroll 1
    for (int idx = tid; idx < TT * TN; idx += NTHREADS)
        xs[(idx >> 5) * XLD + (idx & 31)] = xb[idx];
    if (tid < 96) {
        float ang = (float)tid * 0.06544984694978735f;  // 2*pi/96
        ct[tid] = cosf(ang);
        st[tid] = sinf(ang);
    }
    {
        constexpr int PP[4]  = {8, 6, 4, 12};
        constexpr int W1O[4] = {0, 256, 448, 576};
        constexpr int W2O[4] = {960, 1216, 1408, 1536};
        constexpr int B1O[4] = {1920, 1952, 1984, 2016};
        constexpr int B2O[4] = {2048, 2056, 2062, 2066};
        #pragma unroll 1
        for (int i = 0; i < 4; ++i) {
            const float* w1 = p.ew[4 * i + 0];
            const float* b1 = p.ew[4 * i + 1];
            const float* w2 = p.ew[4 * i + 2];
            const float* b2 = p.ew[4 * i + 3];
            #pragma unroll 1
            for (int j = tid; j < PP[i] * 32; j += NTHREADS) wsh[W1O[i] + j] = w1[j];
            if (tid < 32) wsh[B1O[i] + tid] = b1[tid];
            #pragma unroll 1
            for (int j = tid; j < PP[i] * 32; j += NTHREADS) wsh[W2O[i] + j] = w2[j];
            if (tid < PP[i]) wsh[B2O[i] + tid] = b2[tid];
        }
    }
    if (tid < 32) wst[tid] = p.w_start[tid];
    if (tid == 0) b0sh = p.b_start[0];
    __syncthreads();

    // -------- Phase C+D: DFT (register rotation) + fused wave-parallel top-3 --------
    // thread -> (n = tid>>3, kslot = tid&7); bins k = kslot + 8u, u=0..6
    {
        const int n = tid >> 3;
        const int kslot = tid & 7;
        const int lane = tid & 63;
        float arA[4], aiA[4], arB[3], aiB[3];
        dft_pass<4>(xs, ct, st, n, kslot,      arA, aiA);
        dft_pass<3>(xs, ct, st, n, kslot + 32, arB, aiB);

        // amplitudes of my 7 bins (k==0 -> 0; k>48 invalid -> -1)
        float amp[7];
        #pragma unroll
        for (int u = 0; u < 7; ++u) {
            float r  = (u < 4) ? arA[u] : arB[u - 4];
            float im = (u < 4) ? aiA[u] : aiB[u - 4];
            int k = kslot + 8 * u;
            amp[u] = (k == 0) ? 0.0f : ((k <= 48) ? sqrtf(r * r + im * im) : -1.0f);
        }
        // local descending top-3
        float v1 = -2.0f, v2 = -2.0f, v3 = -2.0f;
        #pragma unroll
        for (int u = 0; u < 7; ++u) {
            float a = amp[u];
            if (a > v1)      { v3 = v2; v2 = v1; v1 = a; }
            else if (a > v2) { v3 = v2; v2 = a; }
            else if (a > v3) { v3 = a; }
        }
        // exact merge of sorted triples across the 8-lane group (d = 1,2,4)
        #pragma unroll
        for (int d = 1; d <= 4; d <<= 1) {
            float b1v = __shfl_xor(v1, d, 64);
            float b2v = __shfl_xor(v2, d, 64);
            float b3v = __shfl_xor(v3, d, 64);
            float m1 = fmaxf(v1, b1v), n1 = fminf(v1, b1v);
            float m2 = fmaxf(v2, b2v), n2 = fminf(v2, b2v);
            float s3 = (v1 > b1v) ? v3 : b3v;
            float c3 = fmaxf(fmaxf(fminf(n1, m2), n2), s3);
            v2 = fmaxf(n1, m2);
            v1 = m1;
            v3 = c3;
        }
        // v3 = exact 3rd-largest amplitude of the 49 bins (thr kth)
        int qc = 0;
        #pragma unroll
        for (int u = 0; u < 7; ++u) qc += (amp[u] >= v3) ? 1 : 0;
        int inc = qc;
        #pragma unroll
        for (int d = 1; d <= 4; d <<= 1) {
            int t = __shfl_up(inc, d, 64);
            if (kslot >= d) inc += t;
        }
        int off = inc - qc;
        int cnt = __shfl(inc, lane | 7, 64);
        if (kslot == 0) selcnt[n] = (cnt < 8) ? cnt : 8;
        int w = off;
        #pragma unroll
        for (int u = 0; u < 7; ++u) {
            int k = kslot + 8 * u;
            if (amp[u] >= v3 && w < 8) {
                float wgt = (k == 0 || k == 48) ? (1.0f / 96.0f) : (2.0f / 96.0f);
                float r  = (u < 4) ? arA[u] : arB[u - 4];
                float im = (u < 4) ? aiA[u] : aiB[u - 4];
                selk[n * 8 + w] = k;
                selr[n * 8 + w] = wgt * r;
                seli[n * 8 + w] = wgt * im;
                w++;
            }
        }
    }
    __syncthreads();

    // ------------- Phase E: trend + season -> x_lin (reduced over n) -------------
    {
        float b0 = b0sh;
        #pragma unroll 1
        for (int j = 0; j < 12; ++j) {
            int pidx = tid + NTHREADS * j;
            int t = pidx >> 5, n = pidx & 31;
            float xv = xs[t * XLD + n];
            // moving averages k=4,8,12 with edge-replicate padding
            #define XC(tt) xs[(((tt) < 0) ? 0 : (((tt) > 95) ? 95 : (tt))) * XLD + n]
            float s4  = XC(t - 1) + xv + XC(t + 1) + XC(t + 2);
            float s8  = s4  + XC(t - 3) + XC(t - 2) + XC(t + 3) + XC(t + 4);
            float s12 = s8  + XC(t - 5) + XC(t - 4) + XC(t + 5) + XC(t + 6);
            #undef XC
            float trend = (s4 * 0.25f + s8 * 0.125f + s12 * (1.0f / 12.0f)) * (1.0f / 3.0f);
            // seasonality from selected bins
            float season = 0.0f;
            int cnt = selcnt[n];
            #pragma unroll 1
            for (int q = 0; q < cnt; ++q) {
                int k = selk[n * 8 + q];
                int m = (t * k) % 96;
                season = fmaf(selr[n * 8 + q], ct[m], season);
                season = fmaf(seli[n * 8 + q], st[m], season);
            }
            float val = (xv + trend + season) * wst[n];
            #pragma unroll
            for (int d = 16; d >= 1; d >>= 1) val += __shfl_xor(val, d, 64);
            if ((tid & 31) == 0) xlin[t] = val + b0;
        }
    }
    __syncthreads();

    // ---------------- Phase F: gating GEMV, all threads ----------------
    {
        int e8 = tid >> 5;          // 0..7: 0-3 -> wg rows, 4-7 -> wn rows
        int tl = tid & 31;
        int eb = e8 & 3;
        const float* W = ((e8 < 4) ? p.wg : p.wn) + eb * 96;
        float acc = 0.0f;
        #pragma unroll
        for (int c = 0; c < 3; ++c)
            acc = fmaf(xlin[tl + 32 * c], W[tl + 32 * c], acc);
        #pragma unroll
        for (int d = 16; d >= 1; d >>= 1) acc += __shfl_xor(acc, d, 64);
        if (tl == 0) gtmp[e8] = acc + ((e8 < 4) ? p.bg[eb] : p.bn[eb]);
    }
    __syncthreads();
    if (tid == 0) {
        float clean[4], stdv[4], noisy[4];
        #pragma unroll
        for (int e = 0; e < 4; ++e) {
            clean[e] = gtmp[e];
            float r = gtmp[4 + e];
            float sp = fmaxf(r, 0.0f) + log1pf(expf(-fabsf(r)));   // softplus
            stdv[e] = fminf(fmaxf(sp + 0.01f, 0.001f), 1000.0f);
            noisy[e] = clean[e] + p.noise[(size_t)b * 4 + e] * stdv[e];
        }
        // top-3 of 4, ties -> lower index first (strict >)
        int i1 = 0, i2 = -1;
        float v1 = -INFINITY, v2 = -INFINITY, v3 = -INFINITY;
        for (int e = 0; e < 4; ++e) if (noisy[e] > v1) { v1 = noisy[e]; i1 = e; }
        for (int e = 0; e < 4; ++e) if (e != i1 && noisy[e] > v2) { v2 = noisy[e]; i2 = e; }
        for (int e = 0; e < 4; ++e) if (e != i1 && e != i2 && noisy[e] > v3) { v3 = noisy[e]; }
        float e2 = expf(v2 - v1);
        float g1 = 1.0f / (1.0f + e2);
        float g2 = e2 * g1;
        float gates[4] = {0.0f, 0.0f, 0.0f, 0.0f};
        gates[i1] = g1; gates[i2] = g2;
        const float inv_sqrt2 = 0.7071067811865476f;
        #pragma unroll
        for (int e = 0; e < 4; ++e) {
            float thr = (noisy[e] > v3) ? v3 : v2;
            float z = (clean[e] - thr) / stdv[e];
            z = fminf(fmaxf(z, -50.0f), 50.0f);
            float pr = 0.5f * (1.0f + erff(z * inv_sqrt2));
            pr = fminf(fmaxf(pr, 0.0f), 1.0f);
            p.part[(size_t)b * 8 + e] = gates[e];
            p.part[(size_t)b * 8 + 4 + e] = pr;
            gsh[e] = gates[e];
        }
    }
    __syncthreads();

    // ------ Phase G: experts into registers (thread owns 12 rows x 1 col), direct store ------
    {
        const int tc = tid >> 5;    // 12-row chunk index 0..7
        const int n  = tid & 31;
        float y[12];
        #pragma unroll
        for (int r = 0; r < 12; ++r) y[r] = 0.0f;
        float g0 = gsh[0], g1 = gsh[1], g2 = gsh[2], g3 = gsh[3];
        if (g0 != 0.0f) {           // P=8: one full + one half patch per chunk
            if (tc & 1) {
                int pb = (3 * tc - 1) >> 1;
                patch_acc<8, 4, 8, 0>(xs, wsh, 0, 960, 1920, 2048, pb,     n, g0, y);
                patch_acc<8, 0, 8, 4>(xs, wsh, 0, 960, 1920, 2048, pb + 1, n, g0, y);
            } else {
                int pb = (3 * tc) >> 1;
                patch_acc<8, 0, 8, 0>(xs, wsh, 0, 960, 1920, 2048, pb,     n, g0, y);
                patch_acc<8, 0, 4, 8>(xs, wsh, 0, 960, 1920, 2048, pb + 1, n, g0, y);
            }
        }
        if (g1 != 0.0f) {           // P=6: two full patches
            patch_acc<6, 0, 6, 0>(xs, wsh, 256, 1216, 1952, 2056, 2 * tc,     n, g1, y);
            patch_acc<6, 0, 6, 6>(xs, wsh, 256, 1216, 1952, 2056, 2 * tc + 1, n, g1, y);
        }
        if (g2 != 0.0f) {           // P=4: three full patches
            patch_acc<4, 0, 4, 0>(xs, wsh, 448, 1408, 1984, 2062, 3 * tc,     n, g2, y);
            patch_acc<4, 0, 4, 4>(xs, wsh, 448, 1408, 1984, 2062, 3 * tc + 1, n, g2, y);
            patch_acc<4, 0, 4, 8>(xs, wsh, 448, 1408, 1984, 2062, 3 * tc + 2, n, g2, y);
        }
        if (g3 != 0.0f) {           // P=12: one full patch
            patch_acc<12, 0, 12, 0>(xs, wsh, 576, 1536, 2016, 2066, tc, n, g3, y);
        }
        float* ob = p.out + (size_t)b * (TT * TN) + (size_t)(12 * tc) * 32 + n;
        #pragma unroll
        for (int r = 0; r < 12; ++r) ob[r * 32] = y[r];
    }
}

__global__ __launch_bounds__(NTHREADS) void ams_finalize(const float* __restrict__ part,
                                                         float* __restrict__ out_loss) {
    __shared__ float red[4][8];
    float acc[8] = {0, 0, 0, 0, 0, 0, 0, 0};
    #pragma unroll 1
    for (int r = threadIdx.x; r < TB; r += NTHREADS) {
        #pragma unroll
        for (int c = 0; c < 8; ++c) acc[c] += part[(size_t)r * 8 + c];
    }
    #pragma unroll
    for (int c = 0; c < 8; ++c) {
        #pragma unroll
        for (int d = 32; d >= 1; d >>= 1) acc[c] += __shfl_xor(acc[c], d, 64);
    }
    int wid = threadIdx.x >> 6;
    if ((threadIdx.x & 63) == 0) {
        #pragma unroll
        for (int c = 0; c < 8; ++c) red[wid][c] = acc[c];
    }
    __syncthreads();
    if (threadIdx.x == 0) {
        float imp[4], load[4];
        #pragma unroll
        for (int c = 0; c < 4; ++c) imp[c]  = red[0][c] + red[1][c] + red[2][c] + red[3][c];
        #pragma unroll
        for (int c = 0; c < 4; ++c) load[c] = red[0][4 + c] + red[1][4 + c] + red[2][4 + c] + red[3][4 + c];
        float mi = (imp[0] + imp[1] + imp[2] + imp[3]) * 0.25f;
        float vi = 0.0f;
        #pragma unroll
        for (int i = 0; i < 4; ++i) { float d = imp[i] - mi; vi += d * d; }
        vi *= (1.0f / 3.0f);
        float ml = (load[0] + load[1] + load[2] + load[3]) * 0.25f;
        float vl = 0.0f;
        #pragma unroll
        for (int i = 0; i < 4; ++i) { float d = load[i] - ml; vl += d * d; }
        vl *= (1.0f / 3.0f);
        float cvi = vi / (mi * mi + 1e-10f);
        float cvl = vl / (ml * ml + 1e-10f);
        out_loss[0] = (cvi + cvl) * 1e-4f;
    }
}

extern "C" void kernel_launch(void* const* d_in, const int* in_sizes, int n_in,
                              void* d_out, int out_size, void* d_ws, size_t ws_size,
                              hipStream_t stream) {
    Params p;
    p.x       = (const float*)d_in[0];
    p.noise   = (const float*)d_in[1];
    p.w_start = (const float*)d_in[2];
    p.b_start = (const float*)d_in[3];
    p.wg      = (const float*)d_in[4];
    p.bg      = (const float*)d_in[5];
    p.wn      = (const float*)d_in[6];
    p.bn      = (const float*)d_in[7];
    for (int i = 0; i < 16; ++i) p.ew[i] = (const float*)d_in[8 + i];
    p.out  = (float*)d_out;
    p.part = (float*)d_ws;   // 4096 * 8 floats = 128 KB of scratch

    ams_main<<<TB, NTHREADS, 0, stream>>>(p);
    ams_finalize<<<1, NTHREADS, 0, stream>>>((const float*)d_ws,
                                             (float*)d_out + (size_t)TB * TT * TN);
}

// Round 8
// 243.121 us; speedup vs baseline: 8.2518x; 1.3536x over previous
//
#include <hip/hip_runtime.h>
#include <math.h>

#define NTHREADS 256
constexpr int TB = 4096;   // batch
constexpr int TT = 96;     // time
constexpr int TN = 32;     // channels
constexpr int XLD = 33;    // padded LDS leading dim

struct Params {
    const float* x; const float* noise;
    const float* w_start; const float* b_start;
    const float* wg; const float* bg; const float* wn; const float* bn;
    const float* ew[16];   // e0_w1,e0_b1,e0_w2,e0_b2, e1_w1, ...
    float* out; float* part;
};

__device__ __forceinline__ float gelu_f(float v) {
    // jax.nn.gelu approximate=True (tanh form); tanh via fast exp
    float u = 0.7978845608028654f * (v + 0.044715f * v * v * v);
    float e = __expf(2.0f * u);
    float th = 1.0f - 2.0f / (e + 1.0f);
    return 0.5f * v * (1.0f + th);
}

// Accumulate one patch of expert P into register chunk y[12].
// Patch rows (patch-local) [L0,L1) map to y[CB + l - L0]. Hidden uses full patch.
template<int P, int L0, int L1, int CB>
__device__ __forceinline__ void patch_acc(const float* __restrict__ xs,
        const float* __restrict__ wsh, int w1o, int w2o, int b1o, int b2o,
        int pb, int n, float g, float (&y)[12]) {
    float v[P];
    #pragma unroll
    for (int l = 0; l < P; ++l) v[l] = xs[(pb * P + l) * XLD + n];
    #pragma unroll 4
    for (int j = 0; j < 32; ++j) {
        float a = wsh[b1o + j];
        #pragma unroll
        for (int l = 0; l < P; ++l) a = fmaf(v[l], wsh[w1o + l * 32 + j], a);
        float gh = g * gelu_f(a);
        #pragma unroll
        for (int l = L0; l < L1; ++l) y[CB + l - L0] = fmaf(gh, wsh[w2o + j * P + l], y[CB + l - L0]);
    }
    #pragma unroll
    for (int l = L0; l < L1; ++l) y[CB + l - L0] = fmaf(g, wsh[b2o + l], y[CB + l - L0]);
}

__global__ __launch_bounds__(NTHREADS) void ams_main(Params p) {
    __shared__ float xs[TT * XLD];       // x2 tile (row t stride 33)  12.7 KB
    __shared__ float ct[96], st[96];     // twiddles cos/sin(2*pi*m/96)
    __shared__ float xlin[96];
    __shared__ float selr[256], seli[256];   // [q][n] transposed layout
    __shared__ int   selk[256];
    __shared__ int   selcnt[32];
    __shared__ float wsh[2080];          // all expert weights  8.3 KB
    __shared__ float wst[32];
    __shared__ float gtmp[8];            // clean[4], rn[4]
    __shared__ float gsh[4];
    __shared__ float b0sh;

    const int tid = threadIdx.x;
    const int b = blockIdx.x;

    // ---------------- Phase A: stage x, weights, twiddles ----------------
    const float* xb = p.x + (size_t)b * (TT * TN);
    #pragma unroll 1
    for (int idx = tid; idx < TT * TN; idx += NTHREADS)
        xs[(idx >> 5) * XLD + (idx & 31)] = xb[idx];
    if (tid < 96) {
        float ang = (float)tid * 0.06544984694978735f;  // 2*pi/96
        ct[tid] = cosf(ang);
        st[tid] = sinf(ang);
    }
    {
        constexpr int PP[4]  = {8, 6, 4, 12};
        constexpr int W1O[4] = {0, 256, 448, 576};
        constexpr int W2O[4] = {960, 1216, 1408, 1536};
        constexpr int B1O[4] = {1920, 1952, 1984, 2016};
        constexpr int B2O[4] = {2048, 2056, 2062, 2066};
        #pragma unroll 1
        for (int i = 0; i < 4; ++i) {
            const float* w1 = p.ew[4 * i + 0];
            const float* b1 = p.ew[4 * i + 1];
            const float* w2 = p.ew[4 * i + 2];
            const float* b2 = p.ew[4 * i + 3];
            #pragma unroll 1
            for (int j = tid; j < PP[i] * 32; j += NTHREADS) wsh[W1O[i] + j] = w1[j];
            if (tid < 32) wsh[B1O[i] + tid] = b1[tid];
            #pragma unroll 1
            for (int j = tid; j < PP[i] * 32; j += NTHREADS) wsh[W2O[i] + j] = w2[j];
            if (tid < PP[i]) wsh[B2O[i] + tid] = b2[tid];
        }
    }
    if (tid < 32) wst[tid] = p.w_start[tid];
    if (tid == 0) b0sh = p.b_start[0];
    __syncthreads();

    // ---- Phase C+D: Cooley-Tukey DFT (96 = 8x12) + fused wave-parallel top-3 ----
    // thread -> (n = tid>>3, kslot = tid&7); bins k = kslot + 8u, u=0..6
    {
        const int n = tid >> 3;
        const int kslot = tid & 7;
        const int lane = tid & 63;

        // Stage 1: S[b] = sum_a x[12a+b] * e^{-2pi i a*kslot/8}  (b = 0..11)
        float Sr[12], Si[12];
        #pragma unroll
        for (int bb = 0; bb < 12; ++bb) { Sr[bb] = 0.0f; Si[bb] = 0.0f; }
        {
            const int step = 12 * kslot;     // twiddle index step per a (mod 96)
            int idx8 = 0;
            #pragma unroll 1
            for (int a = 0; a < 8; ++a) {
                float c8 = ct[idx8], s8 = st[idx8];
                idx8 += step; idx8 = (idx8 >= 96) ? idx8 - 96 : idx8;
                const float* xrow = &xs[(12 * a) * XLD + n];
                #pragma unroll
                for (int bb = 0; bb < 12; ++bb) {
                    float xv = xrow[bb * XLD];
                    Sr[bb] = fmaf(xv, c8, Sr[bb]);
                    Si[bb] = fmaf(xv, s8, Si[bb]);
                }
            }
        }

        // Stage 2: F[k] = sum_b e^{-2pi i b k/96} S[b]; ar=ReF, ai=-ImF
        float ar[7], ai[7];
        #pragma unroll
        for (int u = 0; u < 7; ++u) {
            const int k = kslot + 8 * u;      // k <= 55 < 96; k>48 invalid, masked below
            const float ckv = ct[k];
            const float skv = st[k];
            float cb = 1.0f, sb = 0.0f, arx = 0.0f, aix = 0.0f;
            #pragma unroll
            for (int bb = 0; bb < 12; ++bb) {
                arx = fmaf(cb, Sr[bb], arx);
                arx = fmaf(-sb, Si[bb], arx);
                aix = fmaf(cb, Si[bb], aix);
                aix = fmaf(sb, Sr[bb], aix);
                float cn = fmaf(cb, ckv, -(sb * skv));
                float sn = fmaf(sb, ckv,  cb * skv);
                cb = cn; sb = sn;
            }
            ar[u] = arx; ai[u] = aix;
        }

        // amplitudes of my 7 bins (k==0 -> 0; k>48 invalid -> -1)
        float amp[7];
        #pragma unroll
        for (int u = 0; u < 7; ++u) {
            int k = kslot + 8 * u;
            amp[u] = (k == 0) ? 0.0f : ((k <= 48) ? sqrtf(ar[u] * ar[u] + ai[u] * ai[u]) : -1.0f);
        }
        // local descending top-3
        float v1 = -2.0f, v2 = -2.0f, v3 = -2.0f;
        #pragma unroll
        for (int u = 0; u < 7; ++u) {
            float a = amp[u];
            if (a > v1)      { v3 = v2; v2 = v1; v1 = a; }
            else if (a > v2) { v3 = v2; v2 = a; }
            else if (a > v3) { v3 = a; }
        }
        // exact merge of sorted triples across the 8-lane group (d = 1,2,4)
        #pragma unroll
        for (int d = 1; d <= 4; d <<= 1) {
            float b1v = __shfl_xor(v1, d, 64);
            float b2v = __shfl_xor(v2, d, 64);
            float b3v = __shfl_xor(v3, d, 64);
            float m1 = fmaxf(v1, b1v), n1 = fminf(v1, b1v);
            float m2 = fmaxf(v2, b2v), n2 = fminf(v2, b2v);
            float s3 = (v1 > b1v) ? v3 : b3v;
            float c3 = fmaxf(fmaxf(fminf(n1, m2), n2), s3);
            v2 = fmaxf(n1, m2);
            v1 = m1;
            v3 = c3;
        }
        // v3 = exact 3rd-largest amplitude of the 49 bins
        int qc = 0;
        #pragma unroll
        for (int u = 0; u < 7; ++u) qc += (amp[u] >= v3) ? 1 : 0;
        int inc = qc;
        #pragma unroll
        for (int d = 1; d <= 4; d <<= 1) {
            int t = __shfl_up(inc, d, 64);
            if (kslot >= d) inc += t;
        }
        int off = inc - qc;
        int cnt = __shfl(inc, lane | 7, 64);
        if (kslot == 0) selcnt[n] = (cnt < 8) ? cnt : 8;
        int w = off;
        #pragma unroll
        for (int u = 0; u < 7; ++u) {
            int k = kslot + 8 * u;
            if (amp[u] >= v3 && w < 8) {
                float wgt = (k == 0 || k == 48) ? (1.0f / 96.0f) : (2.0f / 96.0f);
                selk[w * 32 + n] = k;
                selr[w * 32 + n] = wgt * ar[u];
                seli[w * 32 + n] = wgt * ai[u];
                w++;
            }
        }
    }
    __syncthreads();

    // ------------- Phase E: trend + season -> x_lin (reduced over n) -------------
    {
        float b0 = b0sh;
        #pragma unroll 1
        for (int j = 0; j < 12; ++j) {
            int pidx = tid + NTHREADS * j;
            int t = pidx >> 5, n = pidx & 31;
            float xv = xs[t * XLD + n];
            // moving averages k=4,8,12 with edge-replicate padding
            #define XC(tt) xs[(((tt) < 0) ? 0 : (((tt) > 95) ? 95 : (tt))) * XLD + n]
            float s4  = XC(t - 1) + xv + XC(t + 1) + XC(t + 2);
            float s8  = s4  + XC(t - 3) + XC(t - 2) + XC(t + 3) + XC(t + 4);
            float s12 = s8  + XC(t - 5) + XC(t - 4) + XC(t + 5) + XC(t + 6);
            #undef XC
            float trend = (s4 * 0.25f + s8 * 0.125f + s12 * (1.0f / 12.0f)) * (1.0f / 3.0f);
            // seasonality from selected bins
            float season = 0.0f;
            int cnt = selcnt[n];
            #pragma unroll 1
            for (int q = 0; q < cnt; ++q) {
                int k = selk[q * 32 + n];
                int m = (t * k) % 96;
                season = fmaf(selr[q * 32 + n], ct[m], season);
                season = fmaf(seli[q * 32 + n], st[m], season);
            }
            float val = (xv + trend + season) * wst[n];
            #pragma unroll
            for (int d = 16; d >= 1; d >>= 1) val += __shfl_xor(val, d, 64);
            if ((tid & 31) == 0) xlin[t] = val + b0;
        }
    }
    __syncthreads();

    // ---------------- Phase F: gating GEMV, all threads ----------------
    {
        int e8 = tid >> 5;          // 0..7: 0-3 -> wg rows, 4-7 -> wn rows
        int tl = tid & 31;
        int eb = e8 & 3;
        const float* W = ((e8 < 4) ? p.wg : p.wn) + eb * 96;
        float acc = 0.0f;
        #pragma unroll
        for (int c = 0; c < 3; ++c)
            acc = fmaf(xlin[tl + 32 * c], W[tl + 32 * c], acc);
        #pragma unroll
        for (int d = 16; d >= 1; d >>= 1) acc += __shfl_xor(acc, d, 64);
        if (tl == 0) gtmp[e8] = acc + ((e8 < 4) ? p.bg[eb] : p.bn[eb]);
    }
    __syncthreads();
    if (tid == 0) {
        float clean[4], stdv[4], noisy[4];
        #pragma unroll
        for (int e = 0; e < 4; ++e) {
            clean[e] = gtmp[e];
            float r = gtmp[4 + e];
            float sp = fmaxf(r, 0.0f) + log1pf(expf(-fabsf(r)));   // softplus
            stdv[e] = fminf(fmaxf(sp + 0.01f, 0.001f), 1000.0f);
            noisy[e] = clean[e] + p.noise[(size_t)b * 4 + e] * stdv[e];
        }
        // top-3 of 4, ties -> lower index first (strict >)
        int i1 = 0, i2 = -1;
        float v1 = -INFINITY, v2 = -INFINITY, v3 = -INFINITY;
        for (int e = 0; e < 4; ++e) if (noisy[e] > v1) { v1 = noisy[e]; i1 = e; }
        for (int e = 0; e < 4; ++e) if (e != i1 && noisy[e] > v2) { v2 = noisy[e]; i2 = e; }
        for (int e = 0; e < 4; ++e) if (e != i1 && e != i2 && noisy[e] > v3) { v3 = noisy[e]; }
        float e2 = expf(v2 - v1);
        float g1 = 1.0f / (1.0f + e2);
        float g2 = e2 * g1;
        float gates[4] = {0.0f, 0.0f, 0.0f, 0.0f};
        gates[i1] = g1; gates[i2] = g2;
        const float inv_sqrt2 = 0.7071067811865476f;
        #pragma unroll
        for (int e = 0; e < 4; ++e) {
            float thr = (noisy[e] > v3) ? v3 : v2;
            float z = (clean[e] - thr) / stdv[e];
            z = fminf(fmaxf(z, -50.0f), 50.0f);
            float pr = 0.5f * (1.0f + erff(z * inv_sqrt2));
            pr = fminf(fmaxf(pr, 0.0f), 1.0f);
            p.part[(size_t)b * 8 + e] = gates[e];
            p.part[(size_t)b * 8 + 4 + e] = pr;
            gsh[e] = gates[e];
        }
    }
    __syncthreads();

    // ------ Phase G: experts into registers (thread owns 12 rows x 1 col), direct store ------
    {
        const int tc = tid >> 5;    // 12-row chunk index 0..7
        const int n  = tid & 31;
        float y[12];
        #pragma unroll
        for (int r = 0; r < 12; ++r) y[r] = 0.0f;
        float g0 = gsh[0], g1 = gsh[1], g2 = gsh[2], g3 = gsh[3];
        if (g0 != 0.0f) {           // P=8: one full + one half patch per chunk
            if (tc & 1) {
                int pb = (3 * tc - 1) >> 1;
                patch_acc<8, 4, 8, 0>(xs, wsh, 0, 960, 1920, 2048, pb,     n, g0, y);
                patch_acc<8, 0, 8, 4>(xs, wsh, 0, 960, 1920, 2048, pb + 1, n, g0, y);
            } else {
                int pb = (3 * tc) >> 1;
                patch_acc<8, 0, 8, 0>(xs, wsh, 0, 960, 1920, 2048, pb,     n, g0, y);
                patch_acc<8, 0, 4, 8>(xs, wsh, 0, 960, 1920, 2048, pb + 1, n, g0, y);
            }
        }
        if (g1 != 0.0f) {           // P=6: two full patches
            patch_acc<6, 0, 6, 0>(xs, wsh, 256, 1216, 1952, 2056, 2 * tc,     n, g1, y);
            patch_acc<6, 0, 6, 6>(xs, wsh, 256, 1216, 1952, 2056, 2 * tc + 1, n, g1, y);
        }
        if (g2 != 0.0f) {           // P=4: three full patches
            patch_acc<4, 0, 4, 0>(xs, wsh, 448, 1408, 1984, 2062, 3 * tc,     n, g2, y);
            patch_acc<4, 0, 4, 4>(xs, wsh, 448, 1408, 1984, 2062, 3 * tc + 1, n, g2, y);
            patch_acc<4, 0, 4, 8>(xs, wsh, 448, 1408, 1984, 2062, 3 * tc + 2, n, g2, y);
        }
        if (g3 != 0.0f) {           // P=12: one full patch
            patch_acc<12, 0, 12, 0>(xs, wsh, 576, 1536, 2016, 2066, tc, n, g3, y);
        }
        float* ob = p.out + (size_t)b * (TT * TN) + (size_t)(12 * tc) * 32 + n;
        #pragma unroll
        for (int r = 0; r < 12; ++r) ob[r * 32] = y[r];
    }
}

__global__ __launch_bounds__(NTHREADS) void ams_finalize(const float* __restrict__ part,
                                                         float* __restrict__ out_loss) {
    __shared__ float red[4][8];
    float acc[8] = {0, 0, 0, 0, 0, 0, 0, 0};
    #pragma unroll 1
    for (int r = threadIdx.x; r < TB; r += NTHREADS) {
        #pragma unroll
        for (int c = 0; c < 8; ++c) acc[c] += part[(size_t)r * 8 + c];
    }
    #pragma unroll
    for (int c = 0; c < 8; ++c) {
        #pragma unroll
        for (int d = 32; d >= 1; d >>= 1) acc[c] += __shfl_xor(acc[c], d, 64);
    }
    int wid = threadIdx.x >> 6;
    if ((threadIdx.x & 63) == 0) {
        #pragma unroll
        for (int c = 0; c < 8; ++c) red[wid][c] = acc[c];
    }
    __syncthreads();
    if (threadIdx.x == 0) {
        float imp[4], load[4];
        #pragma unroll
        for (int c = 0; c < 4; ++c) imp[c]  = red[0][c] + red[1][c] + red[2][c] + red[3][c];
        #pragma unroll
        for (int c = 0; c < 4; ++c) load[c] = red[0][4 + c] + red[1][4 + c] + red[2][4 + c] + red[3][4 + c];
        float mi = (imp[0] + imp[1] + imp[2] + imp[3]) * 0.25f;
        float vi = 0.0f;
        #pragma unroll
        for (int i = 0; i < 4; ++i) { float d = imp[i] - mi; vi += d * d; }
        vi *= (1.0f / 3.0f);
        float ml = (load[0] + load[1] + load[2] + load[3]) * 0.25f;
        float vl = 0.0f;
        #pragma unroll
        for (int i = 0; i < 4; ++i) { float d = load[i] - ml; vl += d * d; }
        vl *= (1.0f / 3.0f);
        float cvi = vi / (mi * mi + 1e-10f);
        float cvl = vl / (ml * ml + 1e-10f);
        out_loss[0] = (cvi + cvl) * 1e-4f;
    }
}

extern "C" void kernel_launch(void* const* d_in, const int* in_sizes, int n_in,
                              void* d_out, int out_size, void* d_ws, size_t ws_size,
                              hipStream_t stream) {
    Params p;
    p.x       = (const float*)d_in[0];
    p.noise   = (const float*)d_in[1];
    p.w_start = (const float*)d_in[2];
    p.b_start = (const float*)d_in[3];
    p.wg      = (const float*)d_in[4];
    p.bg      = (const float*)d_in[5];
    p.wn      = (const float*)d_in[6];
    p.bn      = (const float*)d_in[7];
    for (int i = 0; i < 16; ++i) p.ew[i] = (const float*)d_in[8 + i];
    p.out  = (float*)d_out;
    p.part = (float*)d_ws;   // 4096 * 8 floats = 128 KB of scratch

    ams_main<<<TB, NTHREADS, 0, stream>>>(p);
    ams_finalize<<<1, NTHREADS, 0, stream>>>((const float*)d_ws,
                                             (float*)d_out + (size_t)TB * TT * TN);
}

// Round 10
// 226.986 us; speedup vs baseline: 8.8383x; 1.0711x over previous
//
#include <hip/hip_runtime.h>
#include <math.h>

#define NTHREADS 256
constexpr int TB = 4096;   // batch
constexpr int TT = 96;     // time
constexpr int TN = 32;     // channels
constexpr int XLD = 33;    // padded LDS leading dim

struct Params {
    const float* x; const float* noise;
    const float* w_start; const float* b_start;
    const float* wg; const float* bg; const float* wn; const float* bn;
    const float* ew[16];   // e0_w1,e0_b1,e0_w2,e0_b2, e1_w1, ...
    float* out; float* part;
};

// gelu tanh-approx via sigmoid identity: 0.5v(1+tanh(u)) = v*sigmoid(2u),
// 2u = 1.5957691216·v + 0.0713548163·v^3.  rcp is the HW approx (~1 ulp).
__device__ __forceinline__ float gelu_f(float v) {
    float v2 = v * v;
    float u2 = fmaf(0.0713548162726278f * v, v2, 1.5957691216057308f * v);
    float t = __expf(-u2);
    return v * __builtin_amdgcn_rcpf(1.0f + t);
}

// Accumulate one patch of expert P into register chunk y[12].
// Patch rows (patch-local) [L0,L1) map to y[CB + l - L0]. Hidden uses full patch.
// Weights read as float4 (ds_read_b128): w1 [l][j] contiguous in j; w2 staged transposed [l][j].
template<int P, int L0, int L1, int CB>
__device__ __forceinline__ void patch_acc(const float* __restrict__ xs,
        const float* __restrict__ wsh, int w1o, int w2to, int b1o, int b2o,
        int pb, int n, float g, float (&y)[12]) {
    float v[P];
    #pragma unroll
    for (int l = 0; l < P; ++l) v[l] = xs[(pb * P + l) * XLD + n];
    #pragma unroll 2
    for (int jb = 0; jb < 8; ++jb) {
        float4 aq = *reinterpret_cast<const float4*>(&wsh[b1o + jb * 4]);
        float a0 = aq.x, a1 = aq.y, a2 = aq.z, a3 = aq.w;
        #pragma unroll
        for (int l = 0; l < P; ++l) {
            float4 w = *reinterpret_cast<const float4*>(&wsh[w1o + l * 32 + jb * 4]);
            a0 = fmaf(v[l], w.x, a0); a1 = fmaf(v[l], w.y, a1);
            a2 = fmaf(v[l], w.z, a2); a3 = fmaf(v[l], w.w, a3);
        }
        float h0 = g * gelu_f(a0), h1 = g * gelu_f(a1);
        float h2 = g * gelu_f(a2), h3 = g * gelu_f(a3);
        #pragma unroll
        for (int l = L0; l < L1; ++l) {
            float4 w = *reinterpret_cast<const float4*>(&wsh[w2to + l * 32 + jb * 4]);
            float acc = y[CB + l - L0];
            acc = fmaf(h0, w.x, acc); acc = fmaf(h1, w.y, acc);
            acc = fmaf(h2, w.z, acc); acc = fmaf(h3, w.w, acc);
            y[CB + l - L0] = acc;
        }
    }
    #pragma unroll
    for (int l = L0; l < L1; ++l) y[CB + l - L0] = fmaf(g, wsh[b2o + l], y[CB + l - L0]);
}

__global__ __launch_bounds__(NTHREADS) void ams_main(Params p) {
    __shared__ float xs[TT * XLD];       // x2 tile (row t stride 33)  12.7 KB
    __shared__ float ct[96], st[96];     // twiddles cos/sin(2*pi*m/96)
    __shared__ float xlin[96];
    __shared__ float selr[256], seli[256];   // [q][n] transposed layout
    __shared__ int   selk[256];
    __shared__ int   selcnt[32];
    __shared__ __align__(16) float wsh[2080];   // expert weights (w2 transposed)  8.3 KB
    __shared__ float wst[32];
    __shared__ float gtmp[8];            // clean[4], rn[4]
    __shared__ float gsh[4];
    __shared__ float b0sh;

    const int tid = threadIdx.x;
    const int b = blockIdx.x;

    // ---------------- Phase A: stage x, weights, twiddles ----------------
    const float* xb = p.x + (size_t)b * (TT * TN);
    #pragma unroll 1
    for (int idx = tid; idx < TT * TN; idx += NTHREADS)
        xs[(idx >> 5) * XLD + (idx & 31)] = xb[idx];
    if (tid < 96) {
        float ang = (float)tid * 0.06544984694978735f;  // 2*pi/96
        ct[tid] = cosf(ang);
        st[tid] = sinf(ang);
    }
    {
        constexpr int PP[4]   = {8, 6, 4, 12};
        constexpr int W1O[4]  = {0, 256, 448, 576};
        constexpr int W2TO[4] = {960, 1216, 1408, 1536};
        constexpr int B1O[4]  = {1920, 1952, 1984, 2016};
        constexpr int B2O[4]  = {2048, 2056, 2062, 2066};
        #pragma unroll 1
        for (int i = 0; i < 4; ++i) {
            const float* w1 = p.ew[4 * i + 0];
            const float* b1 = p.ew[4 * i + 1];
            const float* w2 = p.ew[4 * i + 2];
            const float* b2 = p.ew[4 * i + 3];
            #pragma unroll 1
            for (int j = tid; j < PP[i] * 32; j += NTHREADS) wsh[W1O[i] + j] = w1[j];
            if (tid < 32) wsh[B1O[i] + tid] = b1[tid];
            // w2 transposed: dest [l][j] <- src [j][l]
            #pragma unroll 1
            for (int idx = tid; idx < PP[i] * 32; idx += NTHREADS) {
                int l = idx >> 5, jj = idx & 31;
                wsh[W2TO[i] + idx] = w2[jj * PP[i] + l];
            }
            if (tid < PP[i]) wsh[B2O[i] + tid] = b2[tid];
        }
    }
    if (tid < 32) wst[tid] = p.w_start[tid];
    if (tid == 0) b0sh = p.b_start[0];
    __syncthreads();

    // ---- Phase C+D: Cooley-Tukey DFT (96 = 8x12) + fused wave-parallel top-3 ----
    // thread -> (n = tid>>3, kslot = tid&7); bins k = kslot + 8u, u=0..6
    {
        const int n = tid >> 3;
        const int kslot = tid & 7;
        const int lane = tid & 63;

        // Stage 1: S[b] = sum_a x[12a+b] * e^{-2pi i a*kslot/8}  (b = 0..11)
        float Sr[12], Si[12];
        #pragma unroll
        for (int bb = 0; bb < 12; ++bb) { Sr[bb] = 0.0f; Si[bb] = 0.0f; }
        {
            const int step = 12 * kslot;     // twiddle index step per a (mod 96)
            int idx8 = 0;
            #pragma unroll 1
            for (int a = 0; a < 8; ++a) {
                float c8 = ct[idx8], s8 = st[idx8];
                idx8 += step; idx8 = (idx8 >= 96) ? idx8 - 96 : idx8;
                const float* xrow = &xs[(12 * a) * XLD + n];
                #pragma unroll
                for (int bb = 0; bb < 12; ++bb) {
                    float xv = xrow[bb * XLD];
                    Sr[bb] = fmaf(xv, c8, Sr[bb]);
                    Si[bb] = fmaf(xv, s8, Si[bb]);
                }
            }
        }

        // Stage 2: F[k] = sum_b e^{-2pi i b k/96} S[b]; ar=ReF, ai=-ImF
        float ar[7], ai[7];
        #pragma unroll
        for (int u = 0; u < 7; ++u) {
            const int k = kslot + 8 * u;      // k <= 55 < 96; k>48 invalid, masked below
            const float ckv = ct[k];
            const float skv = st[k];
            float cb = 1.0f, sb = 0.0f, arx = 0.0f, aix = 0.0f;
            #pragma unroll
            for (int bb = 0; bb < 12; ++bb) {
                arx = fmaf(cb, Sr[bb], arx);
                arx = fmaf(-sb, Si[bb], arx);
                aix = fmaf(cb, Si[bb], aix);
                aix = fmaf(sb, Sr[bb], aix);
                float cn = fmaf(cb, ckv, -(sb * skv));
                float sn = fmaf(sb, ckv,  cb * skv);
                cb = cn; sb = sn;
            }
            ar[u] = arx; ai[u] = aix;
        }

        // amplitudes of my 7 bins (k==0 -> 0; k>48 invalid -> -1)
        float amp[7];
        #pragma unroll
        for (int u = 0; u < 7; ++u) {
            int k = kslot + 8 * u;
            amp[u] = (k == 0) ? 0.0f : ((k <= 48) ? sqrtf(ar[u] * ar[u] + ai[u] * ai[u]) : -1.0f);
        }
        // local descending top-3
        float v1 = -2.0f, v2 = -2.0f, v3 = -2.0f;
        #pragma unroll
        for (int u = 0; u < 7; ++u) {
            float a = amp[u];
            if (a > v1)      { v3 = v2; v2 = v1; v1 = a; }
            else if (a > v2) { v3 = v2; v2 = a; }
            else if (a > v3) { v3 = a; }
        }
        // exact merge of sorted triples across the 8-lane group (d = 1,2,4)
        #pragma unroll
        for (int d = 1; d <= 4; d <<= 1) {
            float b1v = __shfl_xor(v1, d, 64);
            float b2v = __shfl_xor(v2, d, 64);
            float b3v = __shfl_xor(v3, d, 64);
            float m1 = fmaxf(v1, b1v), n1 = fminf(v1, b1v);
            float m2 = fmaxf(v2, b2v), n2 = fminf(v2, b2v);
            float s3 = (v1 > b1v) ? v3 : b3v;
            float c3 = fmaxf(fmaxf(fminf(n1, m2), n2), s3);
            v2 = fmaxf(n1, m2);
            v1 = m1;
            v3 = c3;
        }
        // v3 = exact 3rd-largest amplitude of the 49 bins
        int qc = 0;
        #pragma unroll
        for (int u = 0; u < 7; ++u) qc += (amp[u] >= v3) ? 1 : 0;
        int inc = qc;
        #pragma unroll
        for (int d = 1; d <= 4; d <<= 1) {
            int t = __shfl_up(inc, d, 64);
            if (kslot >= d) inc += t;
        }
        int off = inc - qc;
        int cnt = __shfl(inc, lane | 7, 64);
        if (kslot == 0) selcnt[n] = (cnt < 8) ? cnt : 8;
        int w = off;
        #pragma unroll
        for (int u = 0; u < 7; ++u) {
            int k = kslot + 8 * u;
            if (amp[u] >= v3 && w < 8) {
                float wgt = (k == 0 || k == 48) ? (1.0f / 96.0f) : (2.0f / 96.0f);
                selk[w * 32 + n] = k;
                selr[w * 32 + n] = wgt * ar[u];
                seli[w * 32 + n] = wgt * ai[u];
                w++;
            }
        }
    }
    __syncthreads();

    // ------------- Phase E: trend + season -> x_lin (reduced over n) -------------
    {
        float b0 = b0sh;
        #pragma unroll 1
        for (int j = 0; j < 12; ++j) {
            int pidx = tid + NTHREADS * j;
            int t = pidx >> 5, n = pidx & 31;
            float xv = xs[t * XLD + n];
            // moving averages k=4,8,12 with edge-replicate padding
            #define XC(tt) xs[(((tt) < 0) ? 0 : (((tt) > 95) ? 95 : (tt))) * XLD + n]
            float s4  = XC(t - 1) + xv + XC(t + 1) + XC(t + 2);
            float s8  = s4  + XC(t - 3) + XC(t - 2) + XC(t + 3) + XC(t + 4);
            float s12 = s8  + XC(t - 5) + XC(t - 4) + XC(t + 5) + XC(t + 6);
            #undef XC
            float trend = (s4 * 0.25f + s8 * 0.125f + s12 * (1.0f / 12.0f)) * (1.0f / 3.0f);
            // seasonality from selected bins
            float season = 0.0f;
            int cnt = selcnt[n];
            #pragma unroll 1
            for (int q = 0; q < cnt; ++q) {
                int k = selk[q * 32 + n];
                int m = (t * k) % 96;
                season = fmaf(selr[q * 32 + n], ct[m], season);
                season = fmaf(seli[q * 32 + n], st[m], season);
            }
            float val = (xv + trend + season) * wst[n];
            #pragma unroll
            for (int d = 16; d >= 1; d >>= 1) val += __shfl_xor(val, d, 64);
            if ((tid & 31) == 0) xlin[t] = val + b0;
        }
    }
    __syncthreads();

    // ---------------- Phase F: gating GEMV, all threads ----------------
    {
        int e8 = tid >> 5;          // 0..7: 0-3 -> wg rows, 4-7 -> wn rows
        int tl = tid & 31;
        int eb = e8 & 3;
        const float* W = ((e8 < 4) ? p.wg : p.wn) + eb * 96;
        float acc = 0.0f;
        #pragma unroll
        for (int c = 0; c < 3; ++c)
            acc = fmaf(xlin[tl + 32 * c], W[tl + 32 * c], acc);
        #pragma unroll
        for (int d = 16; d >= 1; d >>= 1) acc += __shfl_xor(acc, d, 64);
        if (tl == 0) gtmp[e8] = acc + ((e8 < 4) ? p.bg[eb] : p.bn[eb]);
    }
    __syncthreads();
    if (tid == 0) {
        float clean[4], stdv[4], noisy[4];
        #pragma unroll
        for (int e = 0; e < 4; ++e) {
            clean[e] = gtmp[e];
            float r = gtmp[4 + e];
            float sp = fmaxf(r, 0.0f) + log1pf(expf(-fabsf(r)));   // softplus
            stdv[e] = fminf(fmaxf(sp + 0.01f, 0.001f), 1000.0f);
            noisy[e] = clean[e] + p.noise[(size_t)b * 4 + e] * stdv[e];
        }
        // top-3 of 4, ties -> lower index first (strict >)
        int i1 = 0, i2 = -1;
        float v1 = -INFINITY, v2 = -INFINITY, v3 = -INFINITY;
        for (int e = 0; e < 4; ++e) if (noisy[e] > v1) { v1 = noisy[e]; i1 = e; }
        for (int e = 0; e < 4; ++e) if (e != i1 && noisy[e] > v2) { v2 = noisy[e]; i2 = e; }
        for (int e = 0; e < 4; ++e) if (e != i1 && e != i2 && noisy[e] > v3) { v3 = noisy[e]; }
        float e2 = expf(v2 - v1);
        float g1 = 1.0f / (1.0f + e2);
        float g2 = e2 * g1;
        float gates[4] = {0.0f, 0.0f, 0.0f, 0.0f};
        gates[i1] = g1; gates[i2] = g2;
        const float inv_sqrt2 = 0.7071067811865476f;
        #pragma unroll
        for (int e = 0; e < 4; ++e) {
            float thr = (noisy[e] > v3) ? v3 : v2;
            float z = (clean[e] - thr) / stdv[e];
            z = fminf(fmaxf(z, -50.0f), 50.0f);
            float pr = 0.5f * (1.0f + erff(z * inv_sqrt2));
            pr = fminf(fmaxf(pr, 0.0f), 1.0f);
            p.part[(size_t)b * 8 + e] = gates[e];
            p.part[(size_t)b * 8 + 4 + e] = pr;
            gsh[e] = gates[e];
        }
    }
    __syncthreads();

    // ------ Phase G: experts into registers (thread owns 12 rows x 1 col), direct store ------
    {
        const int tc = tid >> 5;    // 12-row chunk index 0..7
        const int n  = tid & 31;
        float y[12];
        #pragma unroll
        for (int r = 0; r < 12; ++r) y[r] = 0.0f;
        float g0 = gsh[0], g1 = gsh[1], g2 = gsh[2], g3 = gsh[3];
        if (g0 != 0.0f) {           // P=8: one full + one half patch per chunk
            if (tc & 1) {
                int pb = (3 * tc - 1) >> 1;
                patch_acc<8, 4, 8, 0>(xs, wsh, 0, 960, 1920, 2048, pb,     n, g0, y);
                patch_acc<8, 0, 8, 4>(xs, wsh, 0, 960, 1920, 2048, pb + 1, n, g0, y);
            } else {
                int pb = (3 * tc) >> 1;
                patch_acc<8, 0, 8, 0>(xs, wsh, 0, 960, 1920, 2048, pb,     n, g0, y);
                patch_acc<8, 0, 4, 8>(xs, wsh, 0, 960, 1920, 2048, pb + 1, n, g0, y);
            }
        }
        if (g1 != 0.0f) {           // P=6: two full patches
            patch_acc<6, 0, 6, 0>(xs, wsh, 256, 1216, 1952, 2056, 2 * tc,     n, g1, y);
            patch_acc<6, 0, 6, 6>(xs, wsh, 256, 1216, 1952, 2056, 2 * tc + 1, n, g1, y);
        }
        if (g2 != 0.0f) {           // P=4: three full patches
            patch_acc<4, 0, 4, 0>(xs, wsh, 448, 1408, 1984, 2062, 3 * tc,     n, g2, y);
            patch_acc<4, 0, 4, 4>(xs, wsh, 448, 1408, 1984, 2062, 3 * tc + 1, n, g2, y);
            patch_acc<4, 0, 4, 8>(xs, wsh, 448, 1408, 1984, 2062, 3 * tc + 2, n, g2, y);
        }
        if (g3 != 0.0f) {           // P=12: one full patch
            patch_acc<12, 0, 12, 0>(xs, wsh, 576, 1536, 2016, 2066, tc, n, g3, y);
        }
        float* ob = p.out + (size_t)b * (TT * TN) + (size_t)(12 * tc) * 32 + n;
        #pragma unroll
        for (int r = 0; r < 12; ++r) ob[r * 32] = y[r];
    }
}

__global__ __launch_bounds__(NTHREADS) void ams_finalize(const float* __restrict__ part,
                                                         float* __restrict__ out_loss) {
    __shared__ float red[4][8];
    float acc[8] = {0, 0, 0, 0, 0, 0, 0, 0};
    #pragma unroll 1
    for (int r = threadIdx.x; r < TB; r += NTHREADS) {
        #pragma unroll
        for (int c = 0; c < 8; ++c) acc[c] += part[(size_t)r * 8 + c];
    }
    #pragma unroll
    for (int c = 0; c < 8; ++c) {
        #pragma unroll
        for (int d = 32; d >= 1; d >>= 1) acc[c] += __shfl_xor(acc[c], d, 64);
    }
    int wid = threadIdx.x >> 6;
    if ((threadIdx.x & 63) == 0) {
        #pragma unroll
        for (int c = 0; c < 8; ++c) red[wid][c] = acc[c];
    }
    __syncthreads();
    if (threadIdx.x == 0) {
        float imp[4], load[4];
        #pragma unroll
        for (int c = 0; c < 4; ++c) imp[c]  = red[0][c] + red[1][c] + red[2][c] + red[3][c];
        #pragma unroll
        for (int c = 0; c < 4; ++c) load[c] = red[0][4 + c] + red[1][4 + c] + red[2][4 + c] + red[3][4 + c];
        float mi = (imp[0] + imp[1] + imp[2] + imp[3]) * 0.25f;
        float vi = 0.0f;
        #pragma unroll
        for (int i = 0; i < 4; ++i) { float d = imp[i] - mi; vi += d * d; }
        vi *= (1.0f / 3.0f);
        float ml = (load[0] + load[1] + load[2] + load[3]) * 0.25f;
        float vl = 0.0f;
        #pragma unroll
        for (int i = 0; i < 4; ++i) { float d = load[i] - ml; vl += d * d; }
        vl *= (1.0f / 3.0f);
        float cvi = vi / (mi * mi + 1e-10f);
        float cvl = vl / (ml * ml + 1e-10f);
        out_loss[0] = (cvi + cvl) * 1e-4f;
    }
}

extern "C" void kernel_launch(void* const* d_in, const int* in_sizes, int n_in,
                              void* d_out, int out_size, void* d_ws, size_t ws_size,
                              hipStream_t stream) {
    Params p;
    p.x       = (const float*)d_in[0];
    p.noise   = (const float*)d_in[1];
    p.w_start = (const float*)d_in[2];
    p.b_start = (const float*)d_in[3];
    p.wg      = (const float*)d_in[4];
    p.bg      = (const float*)d_in[5];
    p.wn      = (const float*)d_in[6];
    p.bn      = (const float*)d_in[7];
    for (int i = 0; i < 16; ++i) p.ew[i] = (const float*)d_in[8 + i];
    p.out  = (float*)d_out;
    p.part = (float*)d_ws;   // 4096 * 8 floats = 128 KB of scratch

    ams_main<<<TB, NTHREADS, 0, stream>>>(p);
    ams_finalize<<<1, NTHREADS, 0, stream>>>((const float*)d_ws,
                                             (float*)d_out + (size_t)TB * TT * TN);
}

// Round 11
// 221.722 us; speedup vs baseline: 9.0481x; 1.0237x over previous
//
#include <hip/hip_runtime.h>
#include <math.h>

#define NTHREADS 256
constexpr int TB = 4096;   // batch
constexpr int TT = 96;     // time
constexpr int TN = 32;     // channels
constexpr int XLD = 33;    // padded LDS leading dim

struct Params {
    const float* x; const float* noise;
    const float* w_start; const float* b_start;
    const float* wg; const float* bg; const float* wn; const float* bn;
    const float* ew[16];   // e0_w1,e0_b1,e0_w2,e0_b2, e1_w1, ...
    float* out; float* part;
};

// gelu tanh-approx via sigmoid identity: 0.5v(1+tanh(u)) = v*sigmoid(2u)
__device__ __forceinline__ float gelu_f(float v) {
    float v2 = v * v;
    float u2 = fmaf(0.0713548162726278f * v, v2, 1.5957691216057308f * v);
    float t = __expf(-u2);
    return v * __builtin_amdgcn_rcpf(1.0f + t);
}

// Accumulate one patch of expert P into register chunk y[12].
template<int P, int L0, int L1, int CB>
__device__ __forceinline__ void patch_acc(const float* __restrict__ xs,
        const float* __restrict__ wsh, int w1o, int w2to, int b1o, int b2o,
        int pb, int n, float g, float (&y)[12]) {
    float v[P];
    #pragma unroll
    for (int l = 0; l < P; ++l) v[l] = xs[(pb * P + l) * XLD + n];
    #pragma unroll 2
    for (int jb = 0; jb < 8; ++jb) {
        float4 aq = *reinterpret_cast<const float4*>(&wsh[b1o + jb * 4]);
        float a0 = aq.x, a1 = aq.y, a2 = aq.z, a3 = aq.w;
        #pragma unroll
        for (int l = 0; l < P; ++l) {
            float4 w = *reinterpret_cast<const float4*>(&wsh[w1o + l * 32 + jb * 4]);
            a0 = fmaf(v[l], w.x, a0); a1 = fmaf(v[l], w.y, a1);
            a2 = fmaf(v[l], w.z, a2); a3 = fmaf(v[l], w.w, a3);
        }
        float h0 = g * gelu_f(a0), h1 = g * gelu_f(a1);
        float h2 = g * gelu_f(a2), h3 = g * gelu_f(a3);
        #pragma unroll
        for (int l = L0; l < L1; ++l) {
            float4 w = *reinterpret_cast<const float4*>(&wsh[w2to + l * 32 + jb * 4]);
            float acc = y[CB + l - L0];
            acc = fmaf(h0, w.x, acc); acc = fmaf(h1, w.y, acc);
            acc = fmaf(h2, w.z, acc); acc = fmaf(h3, w.w, acc);
            y[CB + l - L0] = acc;
        }
    }
    #pragma unroll
    for (int l = L0; l < L1; ++l) y[CB + l - L0] = fmaf(g, wsh[b2o + l], y[CB + l - L0]);
}

// ================= K1: DFT + selection + trend/season + gating =================
__global__ __launch_bounds__(NTHREADS) void ams_k1(Params p) {
    __shared__ float xs[TT * XLD];       // 12.7 KB
    __shared__ float ct[96], st[96];
    __shared__ float xlin[96];
    __shared__ float selr[256], seli[256];   // [q][n]
    __shared__ int   selk[256];
    __shared__ int   selcnt[32];
    __shared__ float wst[32];
    __shared__ float gtmp[8];
    __shared__ float b0sh;

    const int tid = threadIdx.x;
    const int b = blockIdx.x;

    // ---- stage x, twiddles ----
    const float* xb = p.x + (size_t)b * (TT * TN);
    #pragma unroll 1
    for (int idx = tid; idx < TT * TN; idx += NTHREADS)
        xs[(idx >> 5) * XLD + (idx & 31)] = xb[idx];
    if (tid < 96) {
        float ang = (float)tid * 0.06544984694978735f;  // 2*pi/96
        ct[tid] = cosf(ang);
        st[tid] = sinf(ang);
    }
    if (tid < 32) wst[tid] = p.w_start[tid];
    if (tid == 0) b0sh = p.b_start[0];
    __syncthreads();

    // ---- Cooley-Tukey DFT (96 = 8x12) + fused wave-parallel top-3 ----
    {
        const int n = tid >> 3;
        const int kslot = tid & 7;
        const int lane = tid & 63;

        float Sr[12], Si[12];
        #pragma unroll
        for (int bb = 0; bb < 12; ++bb) { Sr[bb] = 0.0f; Si[bb] = 0.0f; }
        {
            const int step = 12 * kslot;
            int idx8 = 0;
            #pragma unroll 2
            for (int a = 0; a < 8; ++a) {
                float c8 = ct[idx8], s8 = st[idx8];
                idx8 += step; idx8 = (idx8 >= 96) ? idx8 - 96 : idx8;
                const float* xrow = &xs[(12 * a) * XLD + n];
                #pragma unroll
                for (int bb = 0; bb < 12; ++bb) {
                    float xv = xrow[bb * XLD];
                    Sr[bb] = fmaf(xv, c8, Sr[bb]);
                    Si[bb] = fmaf(xv, s8, Si[bb]);
                }
            }
        }

        float ar[7], ai[7];
        #pragma unroll
        for (int u = 0; u < 7; ++u) {
            const int k = kslot + 8 * u;
            const float ckv = ct[k];
            const float skv = st[k];
            float cb = 1.0f, sb = 0.0f, arx = 0.0f, aix = 0.0f;
            #pragma unroll
            for (int bb = 0; bb < 12; ++bb) {
                arx = fmaf(cb, Sr[bb], arx);
                arx = fmaf(-sb, Si[bb], arx);
                aix = fmaf(cb, Si[bb], aix);
                aix = fmaf(sb, Sr[bb], aix);
                float cn = fmaf(cb, ckv, -(sb * skv));
                float sn = fmaf(sb, ckv,  cb * skv);
                cb = cn; sb = sn;
            }
            ar[u] = arx; ai[u] = aix;
        }

        float amp[7];
        #pragma unroll
        for (int u = 0; u < 7; ++u) {
            int k = kslot + 8 * u;
            amp[u] = (k == 0) ? 0.0f : ((k <= 48) ? sqrtf(ar[u] * ar[u] + ai[u] * ai[u]) : -1.0f);
        }
        float v1 = -2.0f, v2 = -2.0f, v3 = -2.0f;
        #pragma unroll
        for (int u = 0; u < 7; ++u) {
            float a = amp[u];
            if (a > v1)      { v3 = v2; v2 = v1; v1 = a; }
            else if (a > v2) { v3 = v2; v2 = a; }
            else if (a > v3) { v3 = a; }
        }
        #pragma unroll
        for (int d = 1; d <= 4; d <<= 1) {
            float b1v = __shfl_xor(v1, d, 64);
            float b2v = __shfl_xor(v2, d, 64);
            float b3v = __shfl_xor(v3, d, 64);
            float m1 = fmaxf(v1, b1v), n1 = fminf(v1, b1v);
            float m2 = fmaxf(v2, b2v), n2 = fminf(v2, b2v);
            float s3 = (v1 > b1v) ? v3 : b3v;
            float c3 = fmaxf(fmaxf(fminf(n1, m2), n2), s3);
            v2 = fmaxf(n1, m2);
            v1 = m1;
            v3 = c3;
        }
        int qc = 0;
        #pragma unroll
        for (int u = 0; u < 7; ++u) qc += (amp[u] >= v3) ? 1 : 0;
        int inc = qc;
        #pragma unroll
        for (int d = 1; d <= 4; d <<= 1) {
            int t = __shfl_up(inc, d, 64);
            if (kslot >= d) inc += t;
        }
        int off = inc - qc;
        int cnt = __shfl(inc, lane | 7, 64);
        if (kslot == 0) selcnt[n] = (cnt < 8) ? cnt : 8;
        int w = off;
        #pragma unroll
        for (int u = 0; u < 7; ++u) {
            int k = kslot + 8 * u;
            if (amp[u] >= v3 && w < 8) {
                float wgt = (k == 0 || k == 48) ? (1.0f / 96.0f) : (2.0f / 96.0f);
                selk[w * 32 + n] = k;
                selr[w * 32 + n] = wgt * ar[u];
                seli[w * 32 + n] = wgt * ai[u];
                w++;
            }
        }
    }
    __syncthreads();

    // ---- trend + season -> x_lin (season via incremental rotators) ----
    {
        float b0 = b0sh;
        const int t0 = tid >> 5;     // t of pass j=0; each pass t += 8
        const int n  = tid & 31;
        const int cnt = selcnt[n];
        // three register-resident rotators (cnt is typically exactly 3)
        float A0 = 0, B0 = 0, c0 = 1, s0 = 0, c80 = 1, s80 = 0;
        float A1 = 0, B1 = 0, c1 = 1, s1 = 0, c81 = 1, s81 = 0;
        float A2 = 0, B2 = 0, c2 = 1, s2 = 0, c82 = 1, s82 = 0;
        #define SETROT(Q, A, B, C, S, C8, S8) \
            if (Q < cnt) { \
                int k = selk[Q * 32 + n]; \
                A = selr[Q * 32 + n]; B = seli[Q * 32 + n]; \
                int m0 = (t0 * k) % 96; C = ct[m0]; S = st[m0]; \
                int m8 = (8 * k) % 96;  C8 = ct[m8]; S8 = st[m8]; \
            }
        SETROT(0, A0, B0, c0, s0, c80, s80)
        SETROT(1, A1, B1, c1, s1, c81, s81)
        SETROT(2, A2, B2, c2, s2, c82, s82)
        #undef SETROT
        #pragma unroll 1
        for (int j = 0; j < 12; ++j) {
            int t = t0 + 8 * j;
            float xv = xs[t * XLD + n];
            #define XC(tt) xs[(((tt) < 0) ? 0 : (((tt) > 95) ? 95 : (tt))) * XLD + n]
            float s4  = XC(t - 1) + xv + XC(t + 1) + XC(t + 2);
            float s8  = s4  + XC(t - 3) + XC(t - 2) + XC(t + 3) + XC(t + 4);
            float s12 = s8  + XC(t - 5) + XC(t - 4) + XC(t + 5) + XC(t + 6);
            #undef XC
            float trend = (s4 * 0.25f + s8 * 0.125f + s12 * (1.0f / 12.0f)) * (1.0f / 3.0f);
            float season = A0 * c0 + B0 * s0 + A1 * c1 + B1 * s1 + A2 * c2 + B2 * s2;
            // rotate each by 8 steps
            float nc0 = fmaf(c0, c80, -(s0 * s80)), ns0 = fmaf(s0, c80, c0 * s80);
            float nc1 = fmaf(c1, c81, -(s1 * s81)), ns1 = fmaf(s1, c81, c1 * s81);
            float nc2 = fmaf(c2, c82, -(s2 * s82)), ns2 = fmaf(s2, c82, c2 * s82);
            c0 = nc0; s0 = ns0; c1 = nc1; s1 = ns1; c2 = nc2; s2 = ns2;
            // rare tie case: more than 3 selected bins
            #pragma unroll 1
            for (int q = 3; q < cnt; ++q) {
                int k = selk[q * 32 + n];
                int m = (t * k) % 96;
                season = fmaf(selr[q * 32 + n], ct[m], season);
                season = fmaf(seli[q * 32 + n], st[m], season);
            }
            float val = (xv + trend + season) * wst[n];
            #pragma unroll
            for (int d = 16; d >= 1; d >>= 1) val += __shfl_xor(val, d, 64);
            if ((tid & 31) == 0) xlin[t] = val + b0;
        }
    }
    __syncthreads();

    // ---- gating GEMV, all threads ----
    {
        int e8 = tid >> 5;
        int tl = tid & 31;
        int eb = e8 & 3;
        const float* W = ((e8 < 4) ? p.wg : p.wn) + eb * 96;
        float acc = 0.0f;
        #pragma unroll
        for (int c = 0; c < 3; ++c)
            acc = fmaf(xlin[tl + 32 * c], W[tl + 32 * c], acc);
        #pragma unroll
        for (int d = 16; d >= 1; d >>= 1) acc += __shfl_xor(acc, d, 64);
        if (tl == 0) gtmp[e8] = acc + ((e8 < 4) ? p.bg[eb] : p.bn[eb]);
    }
    __syncthreads();
    if (tid == 0) {
        float clean[4], stdv[4], noisy[4];
        #pragma unroll
        for (int e = 0; e < 4; ++e) {
            clean[e] = gtmp[e];
            float r = gtmp[4 + e];
            float sp = fmaxf(r, 0.0f) + log1pf(expf(-fabsf(r)));   // softplus
            stdv[e] = fminf(fmaxf(sp + 0.01f, 0.001f), 1000.0f);
            noisy[e] = clean[e] + p.noise[(size_t)b * 4 + e] * stdv[e];
        }
        int i1 = 0, i2 = -1;
        float v1 = -INFINITY, v2 = -INFINITY, v3 = -INFINITY;
        for (int e = 0; e < 4; ++e) if (noisy[e] > v1) { v1 = noisy[e]; i1 = e; }
        for (int e = 0; e < 4; ++e) if (e != i1 && noisy[e] > v2) { v2 = noisy[e]; i2 = e; }
        for (int e = 0; e < 4; ++e) if (e != i1 && e != i2 && noisy[e] > v3) { v3 = noisy[e]; }
        float e2 = expf(v2 - v1);
        float g1 = 1.0f / (1.0f + e2);
        float g2 = e2 * g1;
        float gates[4] = {0.0f, 0.0f, 0.0f, 0.0f};
        gates[i1] = g1; gates[i2] = g2;
        const float inv_sqrt2 = 0.7071067811865476f;
        #pragma unroll
        for (int e = 0; e < 4; ++e) {
            float thr = (noisy[e] > v3) ? v3 : v2;
            float z = (clean[e] - thr) / stdv[e];
            z = fminf(fmaxf(z, -50.0f), 50.0f);
            float pr = 0.5f * (1.0f + erff(z * inv_sqrt2));
            pr = fminf(fmaxf(pr, 0.0f), 1.0f);
            p.part[(size_t)b * 8 + e] = gates[e];
            p.part[(size_t)b * 8 + 4 + e] = pr;
        }
    }
}

// ================= K2: experts =================
__global__ __launch_bounds__(NTHREADS) void ams_k2(Params p) {
    __shared__ float xs[TT * XLD];                 // 12.7 KB
    __shared__ __align__(16) float wsh[2080];      // 8.3 KB (w2 transposed)
    __shared__ float gsh[4];

    const int tid = threadIdx.x;
    const int b = blockIdx.x;

    const float* xb = p.x + (size_t)b * (TT * TN);
    #pragma unroll 1
    for (int idx = tid; idx < TT * TN; idx += NTHREADS)
        xs[(idx >> 5) * XLD + (idx & 31)] = xb[idx];
    {
        constexpr int PP[4]   = {8, 6, 4, 12};
        constexpr int W1O[4]  = {0, 256, 448, 576};
        constexpr int W2TO[4] = {960, 1216, 1408, 1536};
        constexpr int B1O[4]  = {1920, 1952, 1984, 2016};
        constexpr int B2O[4]  = {2048, 2056, 2062, 2066};
        #pragma unroll 1
        for (int i = 0; i < 4; ++i) {
            const float* w1 = p.ew[4 * i + 0];
            const float* b1 = p.ew[4 * i + 1];
            const float* w2 = p.ew[4 * i + 2];
            const float* b2 = p.ew[4 * i + 3];
            #pragma unroll 1
            for (int j = tid; j < PP[i] * 32; j += NTHREADS) wsh[W1O[i] + j] = w1[j];
            if (tid < 32) wsh[B1O[i] + tid] = b1[tid];
            #pragma unroll 1
            for (int idx = tid; idx < PP[i] * 32; idx += NTHREADS) {
                int l = idx >> 5, jj = idx & 31;
                wsh[W2TO[i] + idx] = w2[jj * PP[i] + l];
            }
            if (tid < PP[i]) wsh[B2O[i] + tid] = b2[tid];
        }
    }
    if (tid < 4) gsh[tid] = p.part[(size_t)b * 8 + tid];
    __syncthreads();

    {
        const int tc = tid >> 5;    // 12-row chunk index 0..7
        const int n  = tid & 31;
        float y[12];
        #pragma unroll
        for (int r = 0; r < 12; ++r) y[r] = 0.0f;
        float g0 = gsh[0], g1 = gsh[1], g2 = gsh[2], g3 = gsh[3];
        if (g0 != 0.0f) {           // P=8
            if (tc & 1) {
                int pb = (3 * tc - 1) >> 1;
                patch_acc<8, 4, 8, 0>(xs, wsh, 0, 960, 1920, 2048, pb,     n, g0, y);
                patch_acc<8, 0, 8, 4>(xs, wsh, 0, 960, 1920, 2048, pb + 1, n, g0, y);
            } else {
                int pb = (3 * tc) >> 1;
                patch_acc<8, 0, 8, 0>(xs, wsh, 0, 960, 1920, 2048, pb,     n, g0, y);
                patch_acc<8, 0, 4, 8>(xs, wsh, 0, 960, 1920, 2048, pb + 1, n, g0, y);
            }
        }
        if (g1 != 0.0f) {           // P=6
            patch_acc<6, 0, 6, 0>(xs, wsh, 256, 1216, 1952, 2056, 2 * tc,     n, g1, y);
            patch_acc<6, 0, 6, 6>(xs, wsh, 256, 1216, 1952, 2056, 2 * tc + 1, n, g1, y);
        }
        if (g2 != 0.0f) {           // P=4
            patch_acc<4, 0, 4, 0>(xs, wsh, 448, 1408, 1984, 2062, 3 * tc,     n, g2, y);
            patch_acc<4, 0, 4, 4>(xs, wsh, 448, 1408, 1984, 2062, 3 * tc + 1, n, g2, y);
            patch_acc<4, 0, 4, 8>(xs, wsh, 448, 1408, 1984, 2062, 3 * tc + 2, n, g2, y);
        }
        if (g3 != 0.0f) {           // P=12
            patch_acc<12, 0, 12, 0>(xs, wsh, 576, 1536, 2016, 2066, tc, n, g3, y);
        }
        float* ob = p.out + (size_t)b * (TT * TN) + (size_t)(12 * tc) * 32 + n;
        #pragma unroll
        for (int r = 0; r < 12; ++r) ob[r * 32] = y[r];
    }
}

__global__ __launch_bounds__(NTHREADS) void ams_finalize(const float* __restrict__ part,
                                                         float* __restrict__ out_loss) {
    __shared__ float red[4][8];
    float acc[8] = {0, 0, 0, 0, 0, 0, 0, 0};
    #pragma unroll 1
    for (int r = threadIdx.x; r < TB; r += NTHREADS) {
        #pragma unroll
        for (int c = 0; c < 8; ++c) acc[c] += part[(size_t)r * 8 + c];
    }
    #pragma unroll
    for (int c = 0; c < 8; ++c) {
        #pragma unroll
        for (int d = 32; d >= 1; d >>= 1) acc[c] += __shfl_xor(acc[c], d, 64);
    }
    int wid = threadIdx.x >> 6;
    if ((threadIdx.x & 63) == 0) {
        #pragma unroll
        for (int c = 0; c < 8; ++c) red[wid][c] = acc[c];
    }
    __syncthreads();
    if (threadIdx.x == 0) {
        float imp[4], load[4];
        #pragma unroll
        for (int c = 0; c < 4; ++c) imp[c]  = red[0][c] + red[1][c] + red[2][c] + red[3][c];
        #pragma unroll
        for (int c = 0; c < 4; ++c) load[c] = red[0][4 + c] + red[1][4 + c] + red[2][4 + c] + red[3][4 + c];
        float mi = (imp[0] + imp[1] + imp[2] + imp[3]) * 0.25f;
        float vi = 0.0f;
        #pragma unroll
        for (int i = 0; i < 4; ++i) { float d = imp[i] - mi; vi += d * d; }
        vi *= (1.0f / 3.0f);
        float ml = (load[0] + load[1] + load[2] + load[3]) * 0.25f;
        float vl = 0.0f;
        #pragma unroll
        for (int i = 0; i < 4; ++i) { float d = load[i] - ml; vl += d * d; }
        vl *= (1.0f / 3.0f);
        float cvi = vi / (mi * mi + 1e-10f);
        float cvl = vl / (ml * ml + 1e-10f);
        out_loss[0] = (cvi + cvl) * 1e-4f;
    }
}

extern "C" void kernel_launch(void* const* d_in, const int* in_sizes, int n_in,
                              void* d_out, int out_size, void* d_ws, size_t ws_size,
                              hipStream_t stream) {
    Params p;
    p.x       = (const float*)d_in[0];
    p.noise   = (const float*)d_in[1];
    p.w_start = (const float*)d_in[2];
    p.b_start = (const float*)d_in[3];
    p.wg      = (const float*)d_in[4];
    p.bg      = (const float*)d_in[5];
    p.wn      = (const float*)d_in[6];
    p.bn      = (const float*)d_in[7];
    for (int i = 0; i < 16; ++i) p.ew[i] = (const float*)d_in[8 + i];
    p.out  = (float*)d_out;
    p.part = (float*)d_ws;   // 4096 * 8 floats = 128 KB of scratch

    ams_k1<<<TB, NTHREADS, 0, stream>>>(p);
    ams_k2<<<TB, NTHREADS, 0, stream>>>(p);
    ams_finalize<<<1, NTHREADS, 0, stream>>>((const float*)d_ws,
                                             (float*)d_out + (size_t)TB * TT * TN);
}